// Round 17
// baseline (388.557 us; speedup 1.0000x reference)
//
#include <hip/hip_runtime.h>

// SASRec forward, bf16-MFMA. Round 17 (= round 16 with mg8f re-geometried):
//  - mg8f v2: BM=128, BN=64, 256 thr / 4 waves, LDS = 80 KB (A ring 4x16KB +
//    B ring 4x4KB) -> 2 blocks/CU (was 160KB/1 block -> barrier-idle CU).
//    Slot ring / staging depth / vmcnt ladder identical to verified mg8f
//    (APASS=4, BPASS=1). Block map: XCD swizzle then by=wg>>3, bx=wg&7 so
//    each XCD walks a row-panel band (B L2-resident, A fetched once).
//  - prep_k / mg8 / fattn / mgemm / addln / fc unchanged from round 16.
// Faithful-bug 1: attention computed for batch 0 only (attn[0] broadcast).
// Faithful-bug 2: tril-then-scale with zeros (not -inf); softmax over full row.

typedef __bf16 bf16;
typedef __bf16 bf16x8 __attribute__((ext_vector_type(8)));
typedef __bf16 bf16x4 __attribute__((ext_vector_type(4)));
typedef float  f32x4  __attribute__((ext_vector_type(4)));

#define SEQ 512

__device__ __forceinline__ void gl2lds16(const void* g, void* l) {
    __builtin_amdgcn_global_load_lds(
        (const __attribute__((address_space(1))) void*)g,
        (__attribute__((address_space(3))) void*)l, 16, 0, 0);
}

template<int N> __device__ __forceinline__ void waitvm() {
    if constexpr (N == 0)       asm volatile("s_waitcnt vmcnt(0)" ::: "memory");
    else if constexpr (N == 2)  asm volatile("s_waitcnt vmcnt(2)" ::: "memory");
    else if constexpr (N == 3)  asm volatile("s_waitcnt vmcnt(3)" ::: "memory");
    else if constexpr (N == 4)  asm volatile("s_waitcnt vmcnt(4)" ::: "memory");
    else if constexpr (N == 5)  asm volatile("s_waitcnt vmcnt(5)" ::: "memory");
    else if constexpr (N == 6)  asm volatile("s_waitcnt vmcnt(6)" ::: "memory");
    else if constexpr (N == 8)  asm volatile("s_waitcnt vmcnt(8)" ::: "memory");
    else if constexpr (N == 9)  asm volatile("s_waitcnt vmcnt(9)" ::: "memory");
    else if constexpr (N == 10) asm volatile("s_waitcnt vmcnt(10)" ::: "memory");
    else static_assert(N == 0, "unsupported waitvm");
}

// ============================================================================
// prep_k: 7168 weight-transpose tiles (static decode) + 2 qkv bias packs.
// (unchanged from round 16 — passing)
// ============================================================================
__global__ __launch_bounds__(256)
void prep_k(const float* __restrict__ emb_W, bf16* __restrict__ embWT,
            const float* __restrict__ Wq, const float* __restrict__ Wk,
            const float* __restrict__ Wv, const float* __restrict__ Wo,
            const float* __restrict__ W1, const float* __restrict__ W2,
            bf16* __restrict__ qkvWT, bf16* __restrict__ WoT,
            bf16* __restrict__ W1T, bf16* __restrict__ W2T,
            const float* __restrict__ bq, const float* __restrict__ bk,
            const float* __restrict__ bv, float* __restrict__ qkvB)
{
    const int b = blockIdx.x;
    if (b < 7168) {
        const float* src;
        bf16* dst;
        int K, N, t;
        if (b < 1024) {
            src = emb_W; dst = embWT; K = 2048; N = 512; t = b;
        } else {
            const int bb = b - 1024;
            const int l = bb >= 3072 ? 1 : 0;
            const int r = bb - l * 3072;
            if (r < 256)       { src = Wq + l * 262144;  dst = qkvWT + l * 786432;          K = 512;  N = 512;  t = r; }
            else if (r < 512)  { src = Wk + l * 262144;  dst = qkvWT + l * 786432 + 262144; K = 512;  N = 512;  t = r - 256; }
            else if (r < 768)  { src = Wv + l * 262144;  dst = qkvWT + l * 786432 + 524288; K = 512;  N = 512;  t = r - 512; }
            else if (r < 1024) { src = Wo + l * 262144;  dst = WoT + l * 262144;            K = 512;  N = 512;  t = r - 768; }
            else if (r < 2048) { src = W1 + l * 1048576; dst = W1T + l * 1048576;           K = 512;  N = 2048; t = r - 1024; }
            else               { src = W2 + l * 1048576; dst = W2T + l * 1048576;           K = 2048; N = 512;  t = r - 2048; }
        }
        const int tx = N >> 5;
        const int n0 = (t % tx) * 32, k0 = (t / tx) * 32;
        __shared__ float tl[32][33];
        int r2 = threadIdx.x >> 3, c4 = (threadIdx.x & 7) * 4;
        float4 v = *(const float4*)&src[(long long)(k0 + r2) * N + n0 + c4];
        tl[r2][c4 + 0] = v.x; tl[r2][c4 + 1] = v.y;
        tl[r2][c4 + 2] = v.z; tl[r2][c4 + 3] = v.w;
        __syncthreads();
        int n = threadIdx.x >> 3, kk4 = (threadIdx.x & 7) * 4;
        bf16x4 o;
        o[0] = (bf16)tl[kk4 + 0][n]; o[1] = (bf16)tl[kk4 + 1][n];
        o[2] = (bf16)tl[kk4 + 2][n]; o[3] = (bf16)tl[kk4 + 3][n];
        *(bf16x4*)&dst[(long long)(n0 + n) * K + k0 + kk4] = o;
    } else {
        const int l = b - 7168;
        for (int t2 = threadIdx.x; t2 < 512; t2 += 256) {
            qkvB[l * 1536 + t2]        = bq[l * 512 + t2];
            qkvB[l * 1536 + 512 + t2]  = bk[l * 512 + t2];
            qkvB[l * 1536 + 1024 + t2] = bv[l * 512 + t2];
        }
    }
}

// ============================================================================
// mg8f v2: Cb = A(f32) @ Bt^T + bias + pos. BM=128, BN=64, BK=64.
// 256 threads / 4 waves; LDS 80KB -> 2 blocks/CU. A staged raw f32 via
// global_load_lds (APASS=4), converted at fragment read; B bf16 (BPASS=1).
// Slot ring & vmcnt discipline identical to the verified mg8/mg8f schedule.
// ============================================================================
__global__ __launch_bounds__(256, 2)
void mg8f(const float* __restrict__ Af, int lda,
          const bf16* __restrict__ Bt, int ldb,
          const float* __restrict__ bias, const float* __restrict__ pos,
          bf16* __restrict__ Cb, int ldc, int K)
{
    constexpr int BM = 128, BN = 64;
    constexpr int APASS = 4;              // 16B-loads/thread per A half-slot
    constexpr int BPASS = 1;
    constexpr int AHB = BM * 32 * 4;      // 16384 B (f32, 128 rows x 128 B)
    constexpr int BHB = BN * 64;          // 4096 B (bf16)
    constexpr int MR = 4, NR = 2;         // per-wave 64x32 (WM=2, WN=2)
    __shared__ __align__(1024) char smem[4 * AHB + 4 * BHB];   // 80 KB
    char* ABase = smem;
    char* BBase = smem + 4 * AHB;

    // ---- bijective XCD swizzle (m204), then row-band decomposition ----
    const int gx = gridDim.x, gy = gridDim.y;           // (8, 128)
    const int nwg = gx * gy;
    const int b = blockIdx.y * gx + blockIdx.x;
    const int q = nwg >> 3, r = nwg & 7;
    const int xcd = b & 7, loc = b >> 3;
    const int wg = (xcd < r ? xcd * (q + 1) : r * (q + 1) + (xcd - r) * q) + loc;
    const int bx = wg & 7, by = wg >> 3;   // XCD owns a contiguous by-band
    const int row0 = by * BM, col0 = bx * BN;

    const int tid = threadIdx.x, lane = tid & 63, wv = tid >> 6;
    const int wr = wv >> 1, wc = wv & 1;
    const int fr = lane & 15, fc = lane >> 4;

    // ---- staging sources (per-lane swizzled global, linear LDS dest) ----
    const float* aS[APASS];
    #pragma unroll
    for (int p = 0; p < APASS; ++p) {
        int cL = p * 256 + tid;
        int row = cL >> 3, ch = cL & 7;            // 8 chunks of 16B per 128B row
        aS[p] = Af + (long long)(row0 + row) * lda + ((ch ^ (row & 7)) * 4);
    }
    const bf16* bS0;
    {
        int row = tid >> 2, ch = tid & 3;
        bS0 = Bt + (long long)(col0 + row) * ldb + ((ch ^ (row & 3)) * 8);
    }
    // ---- fragment LDS offsets ----
    int aOff0[MR], aOff1[MR];
    #pragma unroll
    for (int m = 0; m < MR; ++m) {
        int row = wr * 64 + m * 16 + fr;
        aOff0[m] = row * 128 + (((2 * fc)     ^ (row & 7)) * 16);
        aOff1[m] = row * 128 + (((2 * fc + 1) ^ (row & 7)) * 16);
    }
    int bOff[NR];
    #pragma unroll
    for (int n = 0; n < NR; ++n) {
        int row = wc * 32 + n * 16 + fr;
        bOff[n] = row * 64 + ((fc ^ (row & 3)) * 16);
    }

    auto stagePart = [&](int j) {
        const int tau = j >> 2, kh = (j >> 1) & 1, d = tau & 1;
        const int koff = tau * 64 + kh * 32;
        if (!(j & 1)) {
            char* dst = ABase + (d * 2 + kh) * AHB + wv * 1024;
            #pragma unroll
            for (int p = 0; p < APASS; ++p)
                gl2lds16(aS[p] + koff, dst + p * 4096);
        } else {
            char* dst = BBase + (d * 2 + kh) * BHB + wv * 1024;
            gl2lds16(bS0 + koff, dst);
        }
    };

    const int nt = K >> 6;
    const int T = 4 * nt;
    #pragma unroll
    for (int j = 0; j < 6; ++j)
        if (j < T) stagePart(j);
    waitvm<2 * (APASS + BPASS)>();
    __builtin_amdgcn_s_barrier();

    f32x4 acc[MR][NR] = {};
    const int NPH = 2 * nt;
    for (int g = 0; g < NPH; ++g) {
        const int tau = g >> 1, ks = g & 1, d = tau & 1;

        const char* as = ABase + (d * 2 + ks) * AHB;
        const char* bs = BBase + (d * 2 + ks) * BHB;
        bf16x8 a[MR], b2[NR];
        #pragma unroll
        for (int m = 0; m < MR; ++m) {
            f32x4 lo = *(const f32x4*)(as + aOff0[m]);
            f32x4 hi = *(const f32x4*)(as + aOff1[m]);
            bf16x8 w8;
            w8[0] = (bf16)lo[0]; w8[1] = (bf16)lo[1];
            w8[2] = (bf16)lo[2]; w8[3] = (bf16)lo[3];
            w8[4] = (bf16)hi[0]; w8[5] = (bf16)hi[1];
            w8[6] = (bf16)hi[2]; w8[7] = (bf16)hi[3];
            a[m] = w8;
        }
        #pragma unroll
        for (int n = 0; n < NR; ++n) b2[n] = *(const bf16x8*)(bs + bOff[n]);

        if (2 * g + 6 < T) stagePart(2 * g + 6);
        if (2 * g + 7 < T) stagePart(2 * g + 7);

        __builtin_amdgcn_s_setprio(1);
        #pragma unroll
        for (int m = 0; m < MR; ++m)
            #pragma unroll
            for (int n = 0; n < NR; ++n)
                acc[m][n] = __builtin_amdgcn_mfma_f32_16x16x32_bf16(
                    a[m], b2[n], acc[m][n], 0, 0, 0);
        __builtin_amdgcn_s_setprio(0);

        const int rem = T - (2 * g + 4);
        if (rem >= 4)      waitvm<2 * (APASS + BPASS)>();
        else if (rem == 3) waitvm<2 * APASS + BPASS>();
        else if (rem == 2) waitvm<APASS + BPASS>();
        else if (rem == 1) waitvm<APASS>();
        else               waitvm<0>();
        __builtin_amdgcn_s_barrier();
    }

    // ---- coalesced epilogue: acc -> per-wave LDS slice -> 16B stores ----
    float* st = (float*)(smem + wv * 4096);   // f32[16][32] per wave
    const int rowb = row0 + wr * 64;
    const int colb = col0 + wc * 32;
    #pragma unroll
    for (int m = 0; m < MR; ++m) {
        #pragma unroll
        for (int n = 0; n < NR; ++n) {
            int col = colb + n * 16 + fr;
            float bb = bias ? bias[col] : 0.f;
            #pragma unroll
            for (int rr = 0; rr < 4; ++rr) {
                float x = acc[m][n][rr] + bb;
                int rowg = rowb + m * 16 + fc * 4 + rr;
                x += pos[(rowg & 511) * 512 + col];
                st[(fc * 4 + rr) * 32 + n * 16 + fr] = x;
            }
        }
        {
            int row = lane >> 2;               // 0..15
            int c8  = (lane & 3) * 8;          // 0..24
            f32x4 u = *(const f32x4*)&st[row * 32 + c8];
            f32x4 v = *(const f32x4*)&st[row * 32 + c8 + 4];
            bf16x8 w8;
            w8[0] = (bf16)u[0]; w8[1] = (bf16)u[1];
            w8[2] = (bf16)u[2]; w8[3] = (bf16)u[3];
            w8[4] = (bf16)v[0]; w8[5] = (bf16)v[1];
            w8[6] = (bf16)v[2]; w8[7] = (bf16)v[3];
            *(bf16x8*)&Cb[(long long)(rowb + m * 16 + row) * ldc + colb + c8] = w8;
        }
    }
}

// ============================================================================
// fattn: fused attention for batch 0 (unchanged from round 16 — passing)
// ============================================================================
__global__ __launch_bounds__(256, 1)
void fattn(const bf16* __restrict__ qkv,   // [512][1536] (Q|K|V per layer)
           const bf16* __restrict__ VT,    // [8*64][512]
           bf16* __restrict__ attn0b)      // [512][512]
{
    __shared__ __align__(1024) char smem[65536 + 65536 + 4096];
    char* Ks = smem;
    char* Vs = smem + 65536;
    const int h = blockIdx.y;
    const int q0 = blockIdx.x * 64;
    const int tid = threadIdx.x, lane = tid & 63, wv = tid >> 6;
    const int fr = lane & 15, fc = lane >> 4;
    char* Ps = smem + 131072 + wv * 1024;

    {
        const bf16* Kg = qkv + 512 + h * 64;
        #pragma unroll
        for (int p = 0; p < 16; ++p) {
            int row = p * 32 + (tid >> 3);
            int ch  = tid & 7;
            gl2lds16(Kg + (long long)row * 1536 + ((ch ^ (row & 7)) * 8),
                     Ks + p * 4096 + tid * 16);
        }
        const bf16* Vg = VT + (long long)h * 64 * 512;
        #pragma unroll
        for (int p = 0; p < 16; ++p) {
            int row = p * 4 + (tid >> 6);
            int ch  = tid & 63;
            int chg = (ch & ~7) | ((ch & 7) ^ (row & 7));
            gl2lds16(Vg + (long long)row * 512 + chg * 8,
                     Vs + p * 4096 + tid * 16);
        }
    }
    const int q0w = q0 + wv * 16;
    const int qg  = q0w + fr;
    bf16x8 qf[2];
    #pragma unroll
    for (int w = 0; w < 2; ++w)
        qf[w] = *(const bf16x8*)(qkv + (long long)qg * 1536 + h * 64 + w * 32 + fc * 8);

    asm volatile("s_waitcnt vmcnt(0)" ::: "memory");
    __builtin_amdgcn_s_barrier();
    asm volatile("" ::: "memory");

    f32x4 s[32] = {};
    #pragma unroll
    for (int kt = 0; kt < 32; ++kt) {
        #pragma unroll
        for (int w = 0; w < 2; ++w) {
            int row = kt * 16 + fr;
            bf16x8 kf = *(const bf16x8*)(Ks + row * 128 +
                                         (((w * 4 + fc) ^ (row & 7)) * 16));
            s[kt] = __builtin_amdgcn_mfma_f32_16x16x32_bf16(kf, qf[w], s[kt], 0, 0, 0);
        }
    }

    float mx = -3.4e38f;
    #pragma unroll
    for (int kt = 0; kt < 32; ++kt)
        #pragma unroll
        for (int rr = 0; rr < 4; ++rr) {
            int k = kt * 16 + fc * 4 + rr;
            float v = (k <= qg) ? s[kt][rr] * 0.125f : 0.0f;
            s[kt][rr] = v;
            mx = fmaxf(mx, v);
        }
    mx = fmaxf(mx, __shfl_xor(mx, 16));
    mx = fmaxf(mx, __shfl_xor(mx, 32));
    float sum = 0.f;
    #pragma unroll
    for (int kt = 0; kt < 32; ++kt)
        #pragma unroll
        for (int rr = 0; rr < 4; ++rr) {
            float e = __expf(s[kt][rr] - mx);
            s[kt][rr] = e;
            sum += e;
        }
    sum += __shfl_xor(sum, 16);
    sum += __shfl_xor(sum, 32);
    const float inv = 1.0f / sum;

    f32x4 o[4] = {};
    #pragma unroll
    for (int kt2 = 0; kt2 < 16; ++kt2) {
        bf16x4 u0, u1;
        #pragma unroll
        for (int rr = 0; rr < 4; ++rr) {
            u0[rr] = (bf16)(s[2 * kt2][rr] * inv);
            u1[rr] = (bf16)(s[2 * kt2 + 1][rr] * inv);
        }
        *(bf16x4*)(Ps + fr * 64 + ((fc ^ (fr & 7)) * 8))       = u0;
        *(bf16x4*)(Ps + fr * 64 + (((4 + fc) ^ (fr & 7)) * 8)) = u1;
        __threadfence_block();
        bf16x4 lo = *(const bf16x4*)(Ps + fr * 64 + (((2 * fc) ^ (fr & 7)) * 8));
        bf16x4 hi = *(const bf16x4*)(Ps + fr * 64 + (((2 * fc + 1) ^ (fr & 7)) * 8));
        bf16x8 pf;
        pf[0] = lo[0]; pf[1] = lo[1]; pf[2] = lo[2]; pf[3] = lo[3];
        pf[4] = hi[0]; pf[5] = hi[1]; pf[6] = hi[2]; pf[7] = hi[3];
        #pragma unroll
        for (int n = 0; n < 4; ++n) {
            int row = n * 16 + fr;
            int ch  = kt2 * 4 + fc;
            int chs = (ch & ~7) | ((ch & 7) ^ (row & 7));
            bf16x8 vf = *(const bf16x8*)(Vs + row * 1024 + chs * 16);
            o[n] = __builtin_amdgcn_mfma_f32_16x16x32_bf16(pf, vf, o[n], 0, 0, 0);
        }
    }

    #pragma unroll
    for (int n = 0; n < 4; ++n)
        #pragma unroll
        for (int rr = 0; rr < 4; ++rr) {
            int qrow = q0w + fc * 4 + rr;
            attn0b[(long long)qrow * 512 + h * 64 + n * 16 + fr] = (bf16)o[n][rr];
        }
}

// ============================================================================
// mg8: Cb = act(A @ Bt^T + bias) bf16 A (unchanged from round 16 — passing)
// ============================================================================
template<int BN, int ACT>
__global__ __launch_bounds__(512, 1)
void mg8(const bf16* __restrict__ Ab, int lda,
         const bf16* __restrict__ Bt, int ldb,
         const float* __restrict__ bias,
         bf16* __restrict__ Cb, int ldc, int K)
{
    constexpr int BM = 256;
    constexpr int APASS = 2;
    constexpr int BPASS = BN / 128;
    constexpr int AHB = BM * 64;
    constexpr int BHB = BN * 64;
    constexpr int WM = (BN == 256 ? 2 : 4), WN = 8 / WM;
    constexpr int MR = BM / WM / 16;
    constexpr int NR = BN / WN / 16;
    __shared__ __align__(1024) char smem[4 * AHB + 4 * BHB];
    char* ABase = smem;
    char* BBase = smem + 4 * AHB;

    const int gx = gridDim.x, gy = gridDim.y;
    const int nwg = gx * gy;
    const int b = blockIdx.y * gx + blockIdx.x;
    const int q = nwg >> 3, r = nwg & 7;
    const int xcd = b & 7, loc = b >> 3;
    const int wg = (xcd < r ? xcd * (q + 1) : r * (q + 1) + (xcd - r) * q) + loc;
    const int bx = wg % gx, by = wg / gx;
    const int row0 = by * BM, col0 = bx * BN;

    const int tid = threadIdx.x, lane = tid & 63, wv = tid >> 6;
    const int wr = (WM == 2 ? (wv >> 2) : (wv >> 1));
    const int wc = (WM == 2 ? (wv & 3) : (wv & 1));
    const int fr = lane & 15, fc = lane >> 4;

    const bf16* aS[APASS];
    #pragma unroll
    for (int p = 0; p < APASS; ++p) {
        int cL = p * 512 + tid;
        int row = cL >> 2, ch = cL & 3;
        aS[p] = Ab + (long long)(row0 + row) * lda + ((ch ^ (row & 3)) * 8);
    }
    const bf16* bS[BPASS];
    #pragma unroll
    for (int p = 0; p < BPASS; ++p) {
        int cL = p * 512 + tid;
        int row = cL >> 2, ch = cL & 3;
        bS[p] = Bt + (long long)(col0 + row) * ldb + ((ch ^ (row & 3)) * 8);
    }
    int aOff[MR], bOff[NR];
    #pragma unroll
    for (int m = 0; m < MR; ++m) {
        int row = wr * (BM / WM) + m * 16 + fr;
        aOff[m] = row * 64 + ((fc ^ (row & 3)) * 16);
    }
    #pragma unroll
    for (int n = 0; n < NR; ++n) {
        int row = wc * (BN / WN) + n * 16 + fr;
        bOff[n] = row * 64 + ((fc ^ (row & 3)) * 16);
    }

    auto stagePart = [&](int j) {
        const int tau = j >> 2, kh = (j >> 1) & 1, d = tau & 1;
        const int koff = tau * 64 + kh * 32;
        if (!(j & 1)) {
            char* dst = ABase + (d * 2 + kh) * AHB + wv * 1024;
            #pragma unroll
            for (int p = 0; p < APASS; ++p)
                gl2lds16(aS[p] + koff, dst + p * 8192);
        } else {
            char* dst = BBase + (d * 2 + kh) * BHB + wv * 1024;
            #pragma unroll
            for (int p = 0; p < BPASS; ++p)
                gl2lds16(bS[p] + koff, dst + p * 8192);
        }
    };

    const int nt = K >> 6;
    const int T = 4 * nt;
    #pragma unroll
    for (int j = 0; j < 6; ++j)
        if (j < T) stagePart(j);
    waitvm<2 * (APASS + BPASS)>();
    __builtin_amdgcn_s_barrier();

    f32x4 acc[MR][NR] = {};
    const int NPH = 2 * nt;
    for (int g = 0; g < NPH; ++g) {
        const int tau = g >> 1, ks = g & 1, d = tau & 1;

        const char* as = ABase + (d * 2 + ks) * AHB;
        const char* bs = BBase + (d * 2 + ks) * BHB;
        bf16x8 a[MR], b2[NR];
        #pragma unroll
        for (int m = 0; m < MR; ++m) a[m] = *(const bf16x8*)(as + aOff[m]);
        #pragma unroll
        for (int n = 0; n < NR; ++n) b2[n] = *(const bf16x8*)(bs + bOff[n]);

        if (2 * g + 6 < T) stagePart(2 * g + 6);
        if (2 * g + 7 < T) stagePart(2 * g + 7);

        __builtin_amdgcn_s_setprio(1);
        #pragma unroll
        for (int m = 0; m < MR; ++m)
            #pragma unroll
            for (int n = 0; n < NR; ++n)
                acc[m][n] = __builtin_amdgcn_mfma_f32_16x16x32_bf16(
                    a[m], b2[n], acc[m][n], 0, 0, 0);
        __builtin_amdgcn_s_setprio(0);

        const int rem = T - (2 * g + 4);
        if (rem >= 4)      waitvm<2 * (APASS + BPASS)>();
        else if (rem == 3) waitvm<2 * APASS + BPASS>();
        else if (rem == 2) waitvm<APASS + BPASS>();
        else if (rem == 1) waitvm<APASS>();
        else               waitvm<0>();
        __builtin_amdgcn_s_barrier();
    }

    float* st = (float*)(smem + wv * 4096);
    const int rowb = row0 + wr * (BM / WM);
    const int colb = col0 + wc * (BN / WN);
    #pragma unroll
    for (int m = 0; m < MR; ++m) {
        #pragma unroll
        for (int n = 0; n < NR; ++n) {
            int col = colb + n * 16 + fr;
            float bb = bias ? bias[col] : 0.f;
            #pragma unroll
            for (int rr = 0; rr < 4; ++rr) {
                float x = acc[m][n][rr] + bb;
                if constexpr (ACT) x = fmaxf(x, 0.f);
                st[(fc * 4 + rr) * 64 + n * 16 + fr] = x;
            }
        }
        #pragma unroll
        for (int sgi = 0; sgi < 2; ++sgi) {
            int row = sgi * 8 + (lane >> 3);
            int c8 = (lane & 7) * 8;
            f32x4 u = *(const f32x4*)&st[row * 64 + c8];
            f32x4 v = *(const f32x4*)&st[row * 64 + c8 + 4];
            bf16x8 w8;
            w8[0] = (bf16)u[0]; w8[1] = (bf16)u[1];
            w8[2] = (bf16)u[2]; w8[3] = (bf16)u[3];
            w8[4] = (bf16)v[0]; w8[5] = (bf16)v[1];
            w8[6] = (bf16)v[2]; w8[7] = (bf16)v[3];
            *(bf16x8*)&Cb[(long long)(rowb + m * 16 + row) * ldc + colb + c8] = w8;
        }
    }
}

// ============================================================================
// mgemm: 128x64 2-phase template for the small projection GEMMs (unchanged)
// ============================================================================
template<int BM, int BN, int ACT, int CMODE, int CAUSAL>
__global__ __launch_bounds__(256, 4)
void mgemm(const bf16* __restrict__ Ab, int lda, long long sA,
           const bf16* __restrict__ Bt, int ldb, long long sB,
           const float* __restrict__ bias,
           float* __restrict__ Cf, bf16* __restrict__ Cb, int ldc, long long sC,
           int K)
{
    static_assert(BM == 128 && (BN == 128 || BN == 64), "tile");
    const int gx = gridDim.x, gy = gridDim.y;
    const int nwg = gx * gy;
    const int b = blockIdx.y * gx + blockIdx.x;
    const int q = nwg >> 3, r = nwg & 7;
    const int xcd = b & 7, loc = b >> 3;
    const int wg = (xcd < r ? xcd * (q + 1) : r * (q + 1) + (xcd - r) * q) + loc;
    const int bx = wg % gx, by = wg / gx;
    if (CAUSAL && bx * BN > by * BM + (BM - 1)) return;

    constexpr int TM = BM / 32, TN = BN / 32;
    constexpr int AIT = BM / 64, BIT = BN / 64;
    constexpr int ABY = BM * 64;
    constexpr int BBY = BN * 64;
    __shared__ bf16 As[2 * BM * 32];
    __shared__ bf16 Bs[2 * BN * 32];
    char* AsB = (char*)As;
    char* BsB = (char*)Bs;
    const int tid = threadIdx.x;
    const int lane = tid & 63, wv = tid >> 6;
    const int wr = wv >> 1, wc = wv & 1;
    const int fr = lane & 15, fc = lane >> 4;
    const int row0 = by * BM, col0 = bx * BN;
    const int z = blockIdx.z;

    Ab += (long long)z * sA;
    Bt += (long long)z * sB;
    if constexpr (CMODE == 0) Cf += (long long)z * sC;
    else                      Cb += (long long)z * sC;

    f32x4 acc[TM][TN] = {};

    const bf16* aSrc[AIT];
    #pragma unroll
    for (int it = 0; it < AIT; ++it) {
        int cL = it * 256 + tid;
        int row = cL >> 2, ch = cL & 3;
        aSrc[it] = Ab + (long long)(row0 + row) * lda + ((ch ^ (row & 3)) * 8);
    }
    const bf16* bSrc[BIT];
    #pragma unroll
    for (int it = 0; it < BIT; ++it) {
        int cL = it * 256 + tid;
        int row = cL >> 2, ch = cL & 3;
        bSrc[it] = Bt + (long long)(col0 + row) * ldb + ((ch ^ (row & 3)) * 8);
    }
    int aOff[TM], bOff[TN];
    #pragma unroll
    for (int m = 0; m < TM; ++m) {
        int row = wr * (BM / 2) + m * 16 + fr;
        aOff[m] = row * 64 + ((fc ^ (row & 3)) * 16);
    }
    #pragma unroll
    for (int n = 0; n < TN; ++n) {
        int row = wc * (BN / 2) + n * 16 + fr;
        bOff[n] = row * 64 + ((fc ^ (row & 3)) * 16);
    }

    auto stageTo = [&](int buf, int kt) {
        #pragma unroll
        for (int it = 0; it < AIT; ++it)
            gl2lds16(aSrc[it] + kt, AsB + buf * ABY + it * 4096 + wv * 1024);
        #pragma unroll
        for (int it = 0; it < BIT; ++it)
            gl2lds16(bSrc[it] + kt, BsB + buf * BBY + it * 4096 + wv * 1024);
    };

    const int nt = K >> 5;
    stageTo(0, 0);
    asm volatile("s_waitcnt vmcnt(0)" ::: "memory");
    __builtin_amdgcn_s_barrier();
    asm volatile("" ::: "memory");

    int cur = 0;
    for (int t = 0; t < nt; ++t) {
        if (t + 1 < nt) stageTo(cur ^ 1, (t + 1) * 32);
        bf16x8 a[TM], b2[TN];
        #pragma unroll
        for (int m = 0; m < TM; ++m) a[m] = *(const bf16x8*)(AsB + cur * ABY + aOff[m]);
        #pragma unroll
        for (int n = 0; n < TN; ++n) b2[n] = *(const bf16x8*)(BsB + cur * BBY + bOff[n]);
        __builtin_amdgcn_s_setprio(1);
        #pragma unroll
        for (int m = 0; m < TM; ++m)
            #pragma unroll
            for (int n = 0; n < TN; ++n)
                acc[m][n] = __builtin_amdgcn_mfma_f32_16x16x32_bf16(a[m], b2[n], acc[m][n], 0, 0, 0);
        __builtin_amdgcn_s_setprio(0);
        if (t + 1 < nt) {
            asm volatile("s_waitcnt vmcnt(0)" ::: "memory");
            __builtin_amdgcn_s_barrier();
            asm volatile("" ::: "memory");
            cur ^= 1;
        }
    }

    #pragma unroll
    for (int n = 0; n < TN; ++n) {
        int col = col0 + wc * (BN / 2) + n * 16 + fr;
        float bb = bias ? bias[col] : 0.f;
        #pragma unroll
        for (int m = 0; m < TM; ++m) {
            int rbase = row0 + wr * (BM / 2) + m * 16 + fc * 4;
            #pragma unroll
            for (int rr = 0; rr < 4; ++rr) {
                float x = acc[m][n][rr] + bb;
                if constexpr (ACT) x = fmaxf(x, 0.f);
                long long ci = (long long)(rbase + rr) * ldc + col;
                if constexpr (CMODE == 0) Cf[ci] = x;
                else                      Cb[ci] = (bf16)x;
            }
        }
    }
}

// VT[h][d][s] = qkv[s][1024 + h*64 + d]   (bf16 64x64 LDS transpose)
__global__ __launch_bounds__(256)
void vt_k(const bf16* __restrict__ qkv, bf16* __restrict__ VT)
{
    __shared__ bf16 t[64][80];
    int h = blockIdx.y, s0 = blockIdx.x * 64;
    int r = threadIdx.x >> 2, c16 = (threadIdx.x & 3) * 16;
    const bf16* src = qkv + (long long)(s0 + r) * 1536 + 1024 + h * 64 + c16;
    *(bf16x8*)&t[r][c16]     = *(const bf16x8*)src;
    *(bf16x8*)&t[r][c16 + 8] = *(const bf16x8*)(src + 8);
    __syncthreads();
    int d = r, seg = c16;
    bf16 tmp[16];
    #pragma unroll
    for (int j = 0; j < 16; ++j) tmp[j] = t[seg + j][d];
    bf16* dst = VT + ((long long)(h * 64 + d)) * 512 + s0 + seg;
    *(bf16x8*)dst       = *(bf16x8*)&tmp[0];
    *(bf16x8*)(dst + 8) = *(bf16x8*)&tmp[8];
}

// x[row] = LN(x[row] + res[row & mask]) ; 2 rows per 256-thread block
__global__ __launch_bounds__(256)
void addln_k(bf16* __restrict__ xb, const bf16* __restrict__ res,
             unsigned resMask, const float* __restrict__ g,
             const float* __restrict__ bta)
{
    const int tid = threadIdx.x;
    const int sub = tid >> 7;
    const long long row = (long long)blockIdx.x * 2 + sub;
    const int lt = tid & 127;
    const int c = lt * 4;
    bf16x4 xv4 = *(const bf16x4*)&xb[row * 512 + c];
    bf16x4 rv4 = *(const bf16x4*)&res[(long long)(row & resMask) * 512 + c];
    float x0 = (float)xv4[0] + (float)rv4[0];
    float x1 = (float)xv4[1] + (float)rv4[1];
    float x2 = (float)xv4[2] + (float)rv4[2];
    float x3 = (float)xv4[3] + (float)rv4[3];
    float s = x0 + x1 + x2 + x3;
    float qq = x0 * x0 + x1 * x1 + x2 * x2 + x3 * x3;
    #pragma unroll
    for (int off = 32; off; off >>= 1) {
        s += __shfl_xor(s, off);
        qq += __shfl_xor(qq, off);
    }
    __shared__ float rs[4], rq[4];
    if ((tid & 63) == 0) { rs[tid >> 6] = s; rq[tid >> 6] = qq; }
    __syncthreads();
    s = rs[sub * 2] + rs[sub * 2 + 1];
    qq = rq[sub * 2] + rq[sub * 2 + 1];
    float mean = s * (1.0f / 512.0f);
    float var  = qq * (1.0f / 512.0f) - mean * mean;
    float rstd = rsqrtf(var + 1e-5f);
    float4 gv = *(const float4*)&g[c];
    float4 bv = *(const float4*)&bta[c];
    bf16x4 o4;
    o4[0] = (bf16)((x0 - mean) * rstd * gv.x + bv.x);
    o4[1] = (bf16)((x1 - mean) * rstd * gv.y + bv.y);
    o4[2] = (bf16)((x2 - mean) * rstd * gv.z + bv.z);
    o4[3] = (bf16)((x3 - mean) * rstd * gv.w + bv.w);
    *(bf16x4*)&xb[row * 512 + c] = o4;
}

// out[row] = dot(x[row,:], fcW) + fcb   (x bf16)
__global__ __launch_bounds__(256)
void fc_k(const bf16* __restrict__ x, const float* __restrict__ w,
          const float* __restrict__ bb, float* __restrict__ out)
{
    int row  = blockIdx.x * 4 + (threadIdx.x >> 6);
    int lane = threadIdx.x & 63;
    const bf16* xr = x + (long long)row * 512;
    bf16x8 a8 = *(const bf16x8*)&xr[lane * 8];
    float4 w0 = *(const float4*)&w[lane * 8];
    float4 w1 = *(const float4*)&w[lane * 8 + 4];
    float s = (float)a8[0] * w0.x + (float)a8[1] * w0.y
            + (float)a8[2] * w0.z + (float)a8[3] * w0.w
            + (float)a8[4] * w1.x + (float)a8[5] * w1.y
            + (float)a8[6] * w1.z + (float)a8[7] * w1.w;
    #pragma unroll
    for (int off = 32; off; off >>= 1) s += __shfl_xor(s, off);
    if (lane == 0) out[row] = s + bb[0];
}

extern "C" void kernel_launch(void* const* d_in, const int* in_sizes, int n_in,
                              void* d_out, int out_size, void* d_ws, size_t ws_size,
                              hipStream_t stream)
{
    const float* input_seq = (const float*)d_in[0];
    const float* emb_W  = (const float*)d_in[1];
    const float* emb_b  = (const float*)d_in[2];
    const float* pos_emb= (const float*)d_in[3];
    const float* Wq = (const float*)d_in[4];
    const float* bq = (const float*)d_in[5];
    const float* Wk = (const float*)d_in[6];
    const float* bk = (const float*)d_in[7];
    const float* Wv = (const float*)d_in[8];
    const float* bv = (const float*)d_in[9];
    const float* Wo = (const float*)d_in[10];
    const float* bo = (const float*)d_in[11];
    const float* ln1_g = (const float*)d_in[12];
    const float* ln1_b = (const float*)d_in[13];
    const float* W1 = (const float*)d_in[14];
    const float* b1 = (const float*)d_in[15];
    const float* W2 = (const float*)d_in[16];
    const float* b2 = (const float*)d_in[17];
    const float* ln2_g = (const float*)d_in[18];
    const float* ln2_b = (const float*)d_in[19];
    const float* fcW = (const float*)d_in[20];
    const float* fcb = (const float*)d_in[21];
    float* out = (float*)d_out;

    // ---- workspace layout ----
    char* w = (char*)d_ws;
    size_t off = 0;
    auto alloc = [&](size_t bytes) -> void* {
        off = (off + 255) & ~(size_t)255;
        void* p = w + off;
        off += bytes;
        return p;
    };
    bf16*  xb     = (bf16*) alloc(16384ull * 512 * 2);   // 16 MB
    bf16*  embWT  = (bf16*) alloc(512ull * 2048 * 2);
    bf16*  qkvWT  = (bf16*) alloc(2ull * 1536 * 512 * 2);
    bf16*  WoT    = (bf16*) alloc(2ull * 512 * 512 * 2);
    bf16*  W1T    = (bf16*) alloc(2ull * 2048 * 512 * 2);
    bf16*  W2T    = (bf16*) alloc(2ull * 512 * 2048 * 2);
    float* qkvB   = (float*)alloc(2ull * 1536 * 4);
    off = (off + 255) & ~(size_t)255;
    char* dynp = w + off;
    // overlay A (attention phase): qkv + VT + attn outputs (~3 MB)
    bf16*  qkv      = (bf16*)dynp;                         // 512x1536
    bf16*  VT       = (bf16*)(dynp + 1572864);             // 512x512
    bf16*  attn0b   = (bf16*)(dynp + 1572864 + 524288);    // 512x512
    bf16*  attnout0b= (bf16*)(dynp + 1572864 + 524288 + 524288);
    // overlay B (FFN phase): hidden bf16 [16384][2048] + ffout bf16 [16384][512]
    bf16*  hidden = (bf16*)dynp;                           // 67 MB
    bf16*  ffout  = (bf16*)(dynp + 16384ull * 2048 * 2);   // 16 MB

    dim3 blk(256);
    dim3 blk512(512);

    // ---- preprocessing: weight transposes + bias packs ----
    prep_k<<<dim3(7170), blk, 0, stream>>>(
        emb_W, embWT, Wq, Wk, Wv, Wo, W1, W2,
        qkvWT, WoT, W1T, W2T, bq, bk, bv, qkvB);

    // ---- embedding: xb = input_seq(f32) @ emb_W + emb_b + pos_emb ----
    mg8f<<<dim3(8, 128), blk, 0, stream>>>(
        input_seq, 2048, embWT, 2048, emb_b, pos_emb, xb, 512, 2048);

    for (int l = 0; l < 2; ++l) {
        const bf16* qkvWT_l = qkvWT + l * 786432;
        const bf16* WoT_l   = WoT + l * 262144;
        const bf16* W1T_l   = W1T + l * 1048576;
        const bf16* W2T_l   = W2T + l * 1048576;

        // QKV projection (batch 0 rows only), packed N=1536, bf16 out
        mgemm<128, 64, 0, 1, 0><<<dim3(24, 4), blk, 0, stream>>>(
            xb, 512, 0, qkvWT_l, 512, 0, qkvB + l * 1536,
            nullptr, qkv, 1536, 0, 512);
        // V transpose for the fused attention's B-operand
        vt_k<<<dim3(8, 8), blk, 0, stream>>>(qkv, VT);
        // fused QK^T + masked softmax + PV (64 blocks x 4 waves)
        fattn<<<dim3(8, 8), blk, 0, stream>>>(qkv, VT, attn0b);
        // attnout0 = attn0 @ Wo + bo, bf16 out
        mgemm<128, 64, 0, 1, 0><<<dim3(8, 4), blk, 0, stream>>>(
            attn0b, 512, 0, WoT_l, 512, 0, bo + l * 512, nullptr,
            attnout0b, 512, 0, 512);
        // x = LN1(x + attnout0[s]) broadcast
        addln_k<<<dim3(8192), blk, 0, stream>>>(
            xb, attnout0b, 511u, ln1_g + l * 512, ln1_b + l * 512);

        // ---- FFN (full, unchunked) ----
        mg8<256, 1><<<dim3(8, 64), blk512, 0, stream>>>(
            xb, 512, W1T_l, 512, b1 + l * 2048, hidden, 2048, 512);
        mg8<128, 0><<<dim3(4, 64), blk512, 0, stream>>>(
            hidden, 2048, W2T_l, 2048, b2 + l * 512, ffout, 512, 2048);
        addln_k<<<dim3(8192), blk, 0, stream>>>(
            xb, ffout, 0xffffffffu, ln2_g + l * 512, ln2_b + l * 512);
    }

    // ---- out = x @ fc_W + fc_b ----
    fc_k<<<dim3(4096), blk, 0, stream>>>(xb, fcW, fcb, out);
}

// Round 18
// 350.872 us; speedup vs baseline: 1.1074x; 1.1074x over previous
//
#include <hip/hip_runtime.h>

// SASRec forward, bf16-MFMA. Round 18 = REVERT to round 16 (best: 350 us).
// Round 17's mg8f re-geometry (80KB/2blk) regressed (88->147 us: halved
// per-phase compute vs fixed phase overhead + more bank conflicts); the
// 160KB/512-thread mg8f is the verified best embedding variant.
//  - mg8f: embedding GEMM stages A as f32 DIRECTLY into LDS (global_load_lds,
//    8-chunk XOR swizzle, 160KB LDS), converts to bf16 at fragment-read.
//  - prep_k: weights + bias only (7170 blocks).
//  - mg8 / fattn / mgemm / addln / fc as verified in rounds 12-16.
// Faithful-bug 1: attention computed for batch 0 only (attn[0] broadcast).
// Faithful-bug 2: tril-then-scale with zeros (not -inf); softmax over full row.

typedef __bf16 bf16;
typedef __bf16 bf16x8 __attribute__((ext_vector_type(8)));
typedef __bf16 bf16x4 __attribute__((ext_vector_type(4)));
typedef float  f32x4  __attribute__((ext_vector_type(4)));

#define SEQ 512

__device__ __forceinline__ void gl2lds16(const void* g, void* l) {
    __builtin_amdgcn_global_load_lds(
        (const __attribute__((address_space(1))) void*)g,
        (__attribute__((address_space(3))) void*)l, 16, 0, 0);
}

template<int N> __device__ __forceinline__ void waitvm() {
    if constexpr (N == 0)       asm volatile("s_waitcnt vmcnt(0)" ::: "memory");
    else if constexpr (N == 2)  asm volatile("s_waitcnt vmcnt(2)" ::: "memory");
    else if constexpr (N == 3)  asm volatile("s_waitcnt vmcnt(3)" ::: "memory");
    else if constexpr (N == 4)  asm volatile("s_waitcnt vmcnt(4)" ::: "memory");
    else if constexpr (N == 5)  asm volatile("s_waitcnt vmcnt(5)" ::: "memory");
    else if constexpr (N == 6)  asm volatile("s_waitcnt vmcnt(6)" ::: "memory");
    else if constexpr (N == 8)  asm volatile("s_waitcnt vmcnt(8)" ::: "memory");
    else if constexpr (N == 9)  asm volatile("s_waitcnt vmcnt(9)" ::: "memory");
    else if constexpr (N == 10) asm volatile("s_waitcnt vmcnt(10)" ::: "memory");
    else static_assert(N == 0, "unsupported waitvm");
}

// ============================================================================
// prep_k: 7168 weight-transpose tiles (static decode) + 2 qkv bias packs.
// ============================================================================
__global__ __launch_bounds__(256)
void prep_k(const float* __restrict__ emb_W, bf16* __restrict__ embWT,
            const float* __restrict__ Wq, const float* __restrict__ Wk,
            const float* __restrict__ Wv, const float* __restrict__ Wo,
            const float* __restrict__ W1, const float* __restrict__ W2,
            bf16* __restrict__ qkvWT, bf16* __restrict__ WoT,
            bf16* __restrict__ W1T, bf16* __restrict__ W2T,
            const float* __restrict__ bq, const float* __restrict__ bk,
            const float* __restrict__ bv, float* __restrict__ qkvB)
{
    const int b = blockIdx.x;
    if (b < 7168) {
        const float* src;
        bf16* dst;
        int K, N, t;
        if (b < 1024) {
            src = emb_W; dst = embWT; K = 2048; N = 512; t = b;
        } else {
            const int bb = b - 1024;
            const int l = bb >= 3072 ? 1 : 0;
            const int r = bb - l * 3072;
            if (r < 256)       { src = Wq + l * 262144;  dst = qkvWT + l * 786432;          K = 512;  N = 512;  t = r; }
            else if (r < 512)  { src = Wk + l * 262144;  dst = qkvWT + l * 786432 + 262144; K = 512;  N = 512;  t = r - 256; }
            else if (r < 768)  { src = Wv + l * 262144;  dst = qkvWT + l * 786432 + 524288; K = 512;  N = 512;  t = r - 512; }
            else if (r < 1024) { src = Wo + l * 262144;  dst = WoT + l * 262144;            K = 512;  N = 512;  t = r - 768; }
            else if (r < 2048) { src = W1 + l * 1048576; dst = W1T + l * 1048576;           K = 512;  N = 2048; t = r - 1024; }
            else               { src = W2 + l * 1048576; dst = W2T + l * 1048576;           K = 2048; N = 512;  t = r - 2048; }
        }
        const int tx = N >> 5;
        const int n0 = (t % tx) * 32, k0 = (t / tx) * 32;
        __shared__ float tl[32][33];
        int r2 = threadIdx.x >> 3, c4 = (threadIdx.x & 7) * 4;
        float4 v = *(const float4*)&src[(long long)(k0 + r2) * N + n0 + c4];
        tl[r2][c4 + 0] = v.x; tl[r2][c4 + 1] = v.y;
        tl[r2][c4 + 2] = v.z; tl[r2][c4 + 3] = v.w;
        __syncthreads();
        int n = threadIdx.x >> 3, kk4 = (threadIdx.x & 7) * 4;
        bf16x4 o;
        o[0] = (bf16)tl[kk4 + 0][n]; o[1] = (bf16)tl[kk4 + 1][n];
        o[2] = (bf16)tl[kk4 + 2][n]; o[3] = (bf16)tl[kk4 + 3][n];
        *(bf16x4*)&dst[(long long)(n0 + n) * K + k0 + kk4] = o;
    } else {
        const int l = b - 7168;
        for (int t2 = threadIdx.x; t2 < 512; t2 += 256) {
            qkvB[l * 1536 + t2]        = bq[l * 512 + t2];
            qkvB[l * 1536 + 512 + t2]  = bk[l * 512 + t2];
            qkvB[l * 1536 + 1024 + t2] = bv[l * 512 + t2];
        }
    }
}

// ============================================================================
// mg8f: Cb = A(f32) @ Bt^T + bias + pos ; A f32 [M][K] staged RAW into LDS,
// bf16-converted at fragment read. BM=256, BN=128, BK=64. 160 KB LDS.
// Slot ring / staging depth / vmcnt discipline identical to mg8 (verified),
// with APASS=4 (A half-slot = 32 KB), BPASS=1.
// ============================================================================
__global__ __launch_bounds__(512, 1)
void mg8f(const float* __restrict__ Af, int lda,
          const bf16* __restrict__ Bt, int ldb,
          const float* __restrict__ bias, const float* __restrict__ pos,
          bf16* __restrict__ Cb, int ldc, int K)
{
    constexpr int BM = 256, BN = 128;
    constexpr int APASS = 4;              // 16B-loads/thread per A half-slot
    constexpr int BPASS = 1;
    constexpr int AHB = BM * 32 * 4;      // 32768 B (f32)
    constexpr int BHB = BN * 64;          // 8192 B (bf16)
    constexpr int WM = 4, WN = 2;
    constexpr int MR = BM / WM / 16;      // 4
    constexpr int NR = BN / WN / 16;      // 4
    __shared__ __align__(1024) char smem[4 * AHB + 4 * BHB];   // 160 KB
    char* ABase = smem;
    char* BBase = smem + 4 * AHB;

    // ---- bijective XCD swizzle (m204) ----
    const int gx = gridDim.x, gy = gridDim.y;
    const int nwg = gx * gy;
    const int b = blockIdx.y * gx + blockIdx.x;
    const int q = nwg >> 3, r = nwg & 7;
    const int xcd = b & 7, loc = b >> 3;
    const int wg = (xcd < r ? xcd * (q + 1) : r * (q + 1) + (xcd - r) * q) + loc;
    const int bx = wg % gx, by = wg / gx;
    const int row0 = by * BM, col0 = bx * BN;

    const int tid = threadIdx.x, lane = tid & 63, wv = tid >> 6;
    const int wr = wv >> 1, wc = wv & 1;
    const int fr = lane & 15, fc = lane >> 4;

    // ---- staging sources (per-lane swizzled global, linear LDS dest) ----
    const float* aS[APASS];
    #pragma unroll
    for (int p = 0; p < APASS; ++p) {
        int cL = p * 512 + tid;
        int row = cL >> 3, ch = cL & 7;            // 8 chunks of 16B per 128B row
        aS[p] = Af + (long long)(row0 + row) * lda + ((ch ^ (row & 7)) * 4);
    }
    const bf16* bS0;
    {
        int cL = tid;
        int row = cL >> 2, ch = cL & 3;
        bS0 = Bt + (long long)(col0 + row) * ldb + ((ch ^ (row & 3)) * 8);
    }
    // ---- fragment LDS offsets ----
    int aOff0[MR], aOff1[MR];
    #pragma unroll
    for (int m = 0; m < MR; ++m) {
        int row = wr * (BM / WM) + m * 16 + fr;
        aOff0[m] = row * 128 + (((2 * fc)     ^ (row & 7)) * 16);
        aOff1[m] = row * 128 + (((2 * fc + 1) ^ (row & 7)) * 16);
    }
    int bOff[NR];
    #pragma unroll
    for (int n = 0; n < NR; ++n) {
        int row = wc * (BN / WN) + n * 16 + fr;
        bOff[n] = row * 64 + ((fc ^ (row & 3)) * 16);
    }

    auto stagePart = [&](int j) {
        const int tau = j >> 2, kh = (j >> 1) & 1, d = tau & 1;
        const int koff = tau * 64 + kh * 32;
        if (!(j & 1)) {
            char* dst = ABase + (d * 2 + kh) * AHB + wv * 1024;
            #pragma unroll
            for (int p = 0; p < APASS; ++p)
                gl2lds16(aS[p] + koff, dst + p * 8192);
        } else {
            char* dst = BBase + (d * 2 + kh) * BHB + wv * 1024;
            gl2lds16(bS0 + koff, dst);
        }
    };

    const int nt = K >> 6;
    const int T = 4 * nt;
    #pragma unroll
    for (int j = 0; j < 6; ++j)
        if (j < T) stagePart(j);
    waitvm<2 * (APASS + BPASS)>();
    __builtin_amdgcn_s_barrier();

    f32x4 acc[MR][NR] = {};
    const int NPH = 2 * nt;
    for (int g = 0; g < NPH; ++g) {
        const int tau = g >> 1, ks = g & 1, d = tau & 1;

        const char* as = ABase + (d * 2 + ks) * AHB;
        const char* bs = BBase + (d * 2 + ks) * BHB;
        bf16x8 a[MR], b2[NR];
        #pragma unroll
        for (int m = 0; m < MR; ++m) {
            f32x4 lo = *(const f32x4*)(as + aOff0[m]);
            f32x4 hi = *(const f32x4*)(as + aOff1[m]);
            bf16x8 w8;
            w8[0] = (bf16)lo[0]; w8[1] = (bf16)lo[1];
            w8[2] = (bf16)lo[2]; w8[3] = (bf16)lo[3];
            w8[4] = (bf16)hi[0]; w8[5] = (bf16)hi[1];
            w8[6] = (bf16)hi[2]; w8[7] = (bf16)hi[3];
            a[m] = w8;
        }
        #pragma unroll
        for (int n = 0; n < NR; ++n) b2[n] = *(const bf16x8*)(bs + bOff[n]);

        if (2 * g + 6 < T) stagePart(2 * g + 6);
        if (2 * g + 7 < T) stagePart(2 * g + 7);

        __builtin_amdgcn_s_setprio(1);
        #pragma unroll
        for (int m = 0; m < MR; ++m)
            #pragma unroll
            for (int n = 0; n < NR; ++n)
                acc[m][n] = __builtin_amdgcn_mfma_f32_16x16x32_bf16(
                    a[m], b2[n], acc[m][n], 0, 0, 0);
        __builtin_amdgcn_s_setprio(0);

        const int rem = T - (2 * g + 4);
        if (rem >= 4)      waitvm<2 * (APASS + BPASS)>();
        else if (rem == 3) waitvm<2 * APASS + BPASS>();
        else if (rem == 2) waitvm<APASS + BPASS>();
        else if (rem == 1) waitvm<APASS>();
        else               waitvm<0>();
        __builtin_amdgcn_s_barrier();
    }

    // ---- coalesced epilogue: acc -> per-wave LDS slice -> 16B stores ----
    float* st = (float*)(smem + wv * 4096);   // f32[16][64] per wave
    const int rowb = row0 + wr * (BM / WM);
    const int colb = col0 + wc * (BN / WN);
    #pragma unroll
    for (int m = 0; m < MR; ++m) {
        #pragma unroll
        for (int n = 0; n < NR; ++n) {
            int col = colb + n * 16 + fr;
            float bb = bias ? bias[col] : 0.f;
            #pragma unroll
            for (int rr = 0; rr < 4; ++rr) {
                float x = acc[m][n][rr] + bb;
                int rowg = rowb + m * 16 + fc * 4 + rr;
                x += pos[(rowg & 511) * 512 + col];
                st[(fc * 4 + rr) * 64 + n * 16 + fr] = x;
            }
        }
        #pragma unroll
        for (int sgi = 0; sgi < 2; ++sgi) {
            int row = sgi * 8 + (lane >> 3);
            int c8 = (lane & 7) * 8;
            f32x4 u = *(const f32x4*)&st[row * 64 + c8];
            f32x4 v = *(const f32x4*)&st[row * 64 + c8 + 4];
            bf16x8 w8;
            w8[0] = (bf16)u[0]; w8[1] = (bf16)u[1];
            w8[2] = (bf16)u[2]; w8[3] = (bf16)u[3];
            w8[4] = (bf16)v[0]; w8[5] = (bf16)v[1];
            w8[6] = (bf16)v[2]; w8[7] = (bf16)v[3];
            *(bf16x8*)&Cb[(long long)(rowb + m * 16 + row) * ldc + colb + c8] = w8;
        }
    }
}

// ============================================================================
// fattn: fused attention for batch 0 (verified rounds 15/16)
// ============================================================================
__global__ __launch_bounds__(256, 1)
void fattn(const bf16* __restrict__ qkv,   // [512][1536] (Q|K|V per layer)
           const bf16* __restrict__ VT,    // [8*64][512]
           bf16* __restrict__ attn0b)      // [512][512]
{
    __shared__ __align__(1024) char smem[65536 + 65536 + 4096];
    char* Ks = smem;
    char* Vs = smem + 65536;
    const int h = blockIdx.y;
    const int q0 = blockIdx.x * 64;
    const int tid = threadIdx.x, lane = tid & 63, wv = tid >> 6;
    const int fr = lane & 15, fc = lane >> 4;
    char* Ps = smem + 131072 + wv * 1024;

    {
        const bf16* Kg = qkv + 512 + h * 64;
        #pragma unroll
        for (int p = 0; p < 16; ++p) {
            int row = p * 32 + (tid >> 3);
            int ch  = tid & 7;
            gl2lds16(Kg + (long long)row * 1536 + ((ch ^ (row & 7)) * 8),
                     Ks + p * 4096 + tid * 16);
        }
        const bf16* Vg = VT + (long long)h * 64 * 512;
        #pragma unroll
        for (int p = 0; p < 16; ++p) {
            int row = p * 4 + (tid >> 6);
            int ch  = tid & 63;
            int chg = (ch & ~7) | ((ch & 7) ^ (row & 7));
            gl2lds16(Vg + (long long)row * 512 + chg * 8,
                     Vs + p * 4096 + tid * 16);
        }
    }
    const int q0w = q0 + wv * 16;
    const int qg  = q0w + fr;
    bf16x8 qf[2];
    #pragma unroll
    for (int w = 0; w < 2; ++w)
        qf[w] = *(const bf16x8*)(qkv + (long long)qg * 1536 + h * 64 + w * 32 + fc * 8);

    asm volatile("s_waitcnt vmcnt(0)" ::: "memory");
    __builtin_amdgcn_s_barrier();
    asm volatile("" ::: "memory");

    f32x4 s[32] = {};
    #pragma unroll
    for (int kt = 0; kt < 32; ++kt) {
        #pragma unroll
        for (int w = 0; w < 2; ++w) {
            int row = kt * 16 + fr;
            bf16x8 kf = *(const bf16x8*)(Ks + row * 128 +
                                         (((w * 4 + fc) ^ (row & 7)) * 16));
            s[kt] = __builtin_amdgcn_mfma_f32_16x16x32_bf16(kf, qf[w], s[kt], 0, 0, 0);
        }
    }

    float mx = -3.4e38f;
    #pragma unroll
    for (int kt = 0; kt < 32; ++kt)
        #pragma unroll
        for (int rr = 0; rr < 4; ++rr) {
            int k = kt * 16 + fc * 4 + rr;
            float v = (k <= qg) ? s[kt][rr] * 0.125f : 0.0f;
            s[kt][rr] = v;
            mx = fmaxf(mx, v);
        }
    mx = fmaxf(mx, __shfl_xor(mx, 16));
    mx = fmaxf(mx, __shfl_xor(mx, 32));
    float sum = 0.f;
    #pragma unroll
    for (int kt = 0; kt < 32; ++kt)
        #pragma unroll
        for (int rr = 0; rr < 4; ++rr) {
            float e = __expf(s[kt][rr] - mx);
            s[kt][rr] = e;
            sum += e;
        }
    sum += __shfl_xor(sum, 16);
    sum += __shfl_xor(sum, 32);
    const float inv = 1.0f / sum;

    f32x4 o[4] = {};
    #pragma unroll
    for (int kt2 = 0; kt2 < 16; ++kt2) {
        bf16x4 u0, u1;
        #pragma unroll
        for (int rr = 0; rr < 4; ++rr) {
            u0[rr] = (bf16)(s[2 * kt2][rr] * inv);
            u1[rr] = (bf16)(s[2 * kt2 + 1][rr] * inv);
        }
        *(bf16x4*)(Ps + fr * 64 + ((fc ^ (fr & 7)) * 8))       = u0;
        *(bf16x4*)(Ps + fr * 64 + (((4 + fc) ^ (fr & 7)) * 8)) = u1;
        __threadfence_block();
        bf16x4 lo = *(const bf16x4*)(Ps + fr * 64 + (((2 * fc) ^ (fr & 7)) * 8));
        bf16x4 hi = *(const bf16x4*)(Ps + fr * 64 + (((2 * fc + 1) ^ (fr & 7)) * 8));
        bf16x8 pf;
        pf[0] = lo[0]; pf[1] = lo[1]; pf[2] = lo[2]; pf[3] = lo[3];
        pf[4] = hi[0]; pf[5] = hi[1]; pf[6] = hi[2]; pf[7] = hi[3];
        #pragma unroll
        for (int n = 0; n < 4; ++n) {
            int row = n * 16 + fr;
            int ch  = kt2 * 4 + fc;
            int chs = (ch & ~7) | ((ch & 7) ^ (row & 7));
            bf16x8 vf = *(const bf16x8*)(Vs + row * 1024 + chs * 16);
            o[n] = __builtin_amdgcn_mfma_f32_16x16x32_bf16(pf, vf, o[n], 0, 0, 0);
        }
    }

    #pragma unroll
    for (int n = 0; n < 4; ++n)
        #pragma unroll
        for (int rr = 0; rr < 4; ++rr) {
            int qrow = q0w + fc * 4 + rr;
            attn0b[(long long)qrow * 512 + h * 64 + n * 16 + fr] = (bf16)o[n][rr];
        }
}

// ============================================================================
// mg8: Cb = act(A @ Bt^T + bias) bf16 A (verified rounds 12-16)
// ============================================================================
template<int BN, int ACT>
__global__ __launch_bounds__(512, 1)
void mg8(const bf16* __restrict__ Ab, int lda,
         const bf16* __restrict__ Bt, int ldb,
         const float* __restrict__ bias,
         bf16* __restrict__ Cb, int ldc, int K)
{
    constexpr int BM = 256;
    constexpr int APASS = 2;
    constexpr int BPASS = BN / 128;
    constexpr int AHB = BM * 64;
    constexpr int BHB = BN * 64;
    constexpr int WM = (BN == 256 ? 2 : 4), WN = 8 / WM;
    constexpr int MR = BM / WM / 16;
    constexpr int NR = BN / WN / 16;
    __shared__ __align__(1024) char smem[4 * AHB + 4 * BHB];
    char* ABase = smem;
    char* BBase = smem + 4 * AHB;

    const int gx = gridDim.x, gy = gridDim.y;
    const int nwg = gx * gy;
    const int b = blockIdx.y * gx + blockIdx.x;
    const int q = nwg >> 3, r = nwg & 7;
    const int xcd = b & 7, loc = b >> 3;
    const int wg = (xcd < r ? xcd * (q + 1) : r * (q + 1) + (xcd - r) * q) + loc;
    const int bx = wg % gx, by = wg / gx;
    const int row0 = by * BM, col0 = bx * BN;

    const int tid = threadIdx.x, lane = tid & 63, wv = tid >> 6;
    const int wr = (WM == 2 ? (wv >> 2) : (wv >> 1));
    const int wc = (WM == 2 ? (wv & 3) : (wv & 1));
    const int fr = lane & 15, fc = lane >> 4;

    const bf16* aS[APASS];
    #pragma unroll
    for (int p = 0; p < APASS; ++p) {
        int cL = p * 512 + tid;
        int row = cL >> 2, ch = cL & 3;
        aS[p] = Ab + (long long)(row0 + row) * lda + ((ch ^ (row & 3)) * 8);
    }
    const bf16* bS[BPASS];
    #pragma unroll
    for (int p = 0; p < BPASS; ++p) {
        int cL = p * 512 + tid;
        int row = cL >> 2, ch = cL & 3;
        bS[p] = Bt + (long long)(col0 + row) * ldb + ((ch ^ (row & 3)) * 8);
    }
    int aOff[MR], bOff[NR];
    #pragma unroll
    for (int m = 0; m < MR; ++m) {
        int row = wr * (BM / WM) + m * 16 + fr;
        aOff[m] = row * 64 + ((fc ^ (row & 3)) * 16);
    }
    #pragma unroll
    for (int n = 0; n < NR; ++n) {
        int row = wc * (BN / WN) + n * 16 + fr;
        bOff[n] = row * 64 + ((fc ^ (row & 3)) * 16);
    }

    auto stagePart = [&](int j) {
        const int tau = j >> 2, kh = (j >> 1) & 1, d = tau & 1;
        const int koff = tau * 64 + kh * 32;
        if (!(j & 1)) {
            char* dst = ABase + (d * 2 + kh) * AHB + wv * 1024;
            #pragma unroll
            for (int p = 0; p < APASS; ++p)
                gl2lds16(aS[p] + koff, dst + p * 8192);
        } else {
            char* dst = BBase + (d * 2 + kh) * BHB + wv * 1024;
            #pragma unroll
            for (int p = 0; p < BPASS; ++p)
                gl2lds16(bS[p] + koff, dst + p * 8192);
        }
    };

    const int nt = K >> 6;
    const int T = 4 * nt;
    #pragma unroll
    for (int j = 0; j < 6; ++j)
        if (j < T) stagePart(j);
    waitvm<2 * (APASS + BPASS)>();
    __builtin_amdgcn_s_barrier();

    f32x4 acc[MR][NR] = {};
    const int NPH = 2 * nt;
    for (int g = 0; g < NPH; ++g) {
        const int tau = g >> 1, ks = g & 1, d = tau & 1;

        const char* as = ABase + (d * 2 + ks) * AHB;
        const char* bs = BBase + (d * 2 + ks) * BHB;
        bf16x8 a[MR], b2[NR];
        #pragma unroll
        for (int m = 0; m < MR; ++m) a[m] = *(const bf16x8*)(as + aOff[m]);
        #pragma unroll
        for (int n = 0; n < NR; ++n) b2[n] = *(const bf16x8*)(bs + bOff[n]);

        if (2 * g + 6 < T) stagePart(2 * g + 6);
        if (2 * g + 7 < T) stagePart(2 * g + 7);

        __builtin_amdgcn_s_setprio(1);
        #pragma unroll
        for (int m = 0; m < MR; ++m)
            #pragma unroll
            for (int n = 0; n < NR; ++n)
                acc[m][n] = __builtin_amdgcn_mfma_f32_16x16x32_bf16(
                    a[m], b2[n], acc[m][n], 0, 0, 0);
        __builtin_amdgcn_s_setprio(0);

        const int rem = T - (2 * g + 4);
        if (rem >= 4)      waitvm<2 * (APASS + BPASS)>();
        else if (rem == 3) waitvm<2 * APASS + BPASS>();
        else if (rem == 2) waitvm<APASS + BPASS>();
        else if (rem == 1) waitvm<APASS>();
        else               waitvm<0>();
        __builtin_amdgcn_s_barrier();
    }

    float* st = (float*)(smem + wv * 4096);
    const int rowb = row0 + wr * (BM / WM);
    const int colb = col0 + wc * (BN / WN);
    #pragma unroll
    for (int m = 0; m < MR; ++m) {
        #pragma unroll
        for (int n = 0; n < NR; ++n) {
            int col = colb + n * 16 + fr;
            float bb = bias ? bias[col] : 0.f;
            #pragma unroll
            for (int rr = 0; rr < 4; ++rr) {
                float x = acc[m][n][rr] + bb;
                if constexpr (ACT) x = fmaxf(x, 0.f);
                st[(fc * 4 + rr) * 64 + n * 16 + fr] = x;
            }
        }
        #pragma unroll
        for (int sgi = 0; sgi < 2; ++sgi) {
            int row = sgi * 8 + (lane >> 3);
            int c8 = (lane & 7) * 8;
            f32x4 u = *(const f32x4*)&st[row * 64 + c8];
            f32x4 v = *(const f32x4*)&st[row * 64 + c8 + 4];
            bf16x8 w8;
            w8[0] = (bf16)u[0]; w8[1] = (bf16)u[1];
            w8[2] = (bf16)u[2]; w8[3] = (bf16)u[3];
            w8[4] = (bf16)v[0]; w8[5] = (bf16)v[1];
            w8[6] = (bf16)v[2]; w8[7] = (bf16)v[3];
            *(bf16x8*)&Cb[(long long)(rowb + m * 16 + row) * ldc + colb + c8] = w8;
        }
    }
}

// ============================================================================
// mgemm: 128x64 2-phase template for the small projection GEMMs
// ============================================================================
template<int BM, int BN, int ACT, int CMODE, int CAUSAL>
__global__ __launch_bounds__(256, 4)
void mgemm(const bf16* __restrict__ Ab, int lda, long long sA,
           const bf16* __restrict__ Bt, int ldb, long long sB,
           const float* __restrict__ bias,
           float* __restrict__ Cf, bf16* __restrict__ Cb, int ldc, long long sC,
           int K)
{
    static_assert(BM == 128 && (BN == 128 || BN == 64), "tile");
    const int gx = gridDim.x, gy = gridDim.y;
    const int nwg = gx * gy;
    const int b = blockIdx.y * gx + blockIdx.x;
    const int q = nwg >> 3, r = nwg & 7;
    const int xcd = b & 7, loc = b >> 3;
    const int wg = (xcd < r ? xcd * (q + 1) : r * (q + 1) + (xcd - r) * q) + loc;
    const int bx = wg % gx, by = wg / gx;
    if (CAUSAL && bx * BN > by * BM + (BM - 1)) return;

    constexpr int TM = BM / 32, TN = BN / 32;
    constexpr int AIT = BM / 64, BIT = BN / 64;
    constexpr int ABY = BM * 64;
    constexpr int BBY = BN * 64;
    __shared__ bf16 As[2 * BM * 32];
    __shared__ bf16 Bs[2 * BN * 32];
    char* AsB = (char*)As;
    char* BsB = (char*)Bs;
    const int tid = threadIdx.x;
    const int lane = tid & 63, wv = tid >> 6;
    const int wr = wv >> 1, wc = wv & 1;
    const int fr = lane & 15, fc = lane >> 4;
    const int row0 = by * BM, col0 = bx * BN;
    const int z = blockIdx.z;

    Ab += (long long)z * sA;
    Bt += (long long)z * sB;
    if constexpr (CMODE == 0) Cf += (long long)z * sC;
    else                      Cb += (long long)z * sC;

    f32x4 acc[TM][TN] = {};

    const bf16* aSrc[AIT];
    #pragma unroll
    for (int it = 0; it < AIT; ++it) {
        int cL = it * 256 + tid;
        int row = cL >> 2, ch = cL & 3;
        aSrc[it] = Ab + (long long)(row0 + row) * lda + ((ch ^ (row & 3)) * 8);
    }
    const bf16* bSrc[BIT];
    #pragma unroll
    for (int it = 0; it < BIT; ++it) {
        int cL = it * 256 + tid;
        int row = cL >> 2, ch = cL & 3;
        bSrc[it] = Bt + (long long)(col0 + row) * ldb + ((ch ^ (row & 3)) * 8);
    }
    int aOff[TM], bOff[TN];
    #pragma unroll
    for (int m = 0; m < TM; ++m) {
        int row = wr * (BM / 2) + m * 16 + fr;
        aOff[m] = row * 64 + ((fc ^ (row & 3)) * 16);
    }
    #pragma unroll
    for (int n = 0; n < TN; ++n) {
        int row = wc * (BN / 2) + n * 16 + fr;
        bOff[n] = row * 64 + ((fc ^ (row & 3)) * 16);
    }

    auto stageTo = [&](int buf, int kt) {
        #pragma unroll
        for (int it = 0; it < AIT; ++it)
            gl2lds16(aSrc[it] + kt, AsB + buf * ABY + it * 4096 + wv * 1024);
        #pragma unroll
        for (int it = 0; it < BIT; ++it)
            gl2lds16(bSrc[it] + kt, BsB + buf * BBY + it * 4096 + wv * 1024);
    };

    const int nt = K >> 5;
    stageTo(0, 0);
    asm volatile("s_waitcnt vmcnt(0)" ::: "memory");
    __builtin_amdgcn_s_barrier();
    asm volatile("" ::: "memory");

    int cur = 0;
    for (int t = 0; t < nt; ++t) {
        if (t + 1 < nt) stageTo(cur ^ 1, (t + 1) * 32);
        bf16x8 a[TM], b2[TN];
        #pragma unroll
        for (int m = 0; m < TM; ++m) a[m] = *(const bf16x8*)(AsB + cur * ABY + aOff[m]);
        #pragma unroll
        for (int n = 0; n < TN; ++n) b2[n] = *(const bf16x8*)(BsB + cur * BBY + bOff[n]);
        __builtin_amdgcn_s_setprio(1);
        #pragma unroll
        for (int m = 0; m < TM; ++m)
            #pragma unroll
            for (int n = 0; n < TN; ++n)
                acc[m][n] = __builtin_amdgcn_mfma_f32_16x16x32_bf16(a[m], b2[n], acc[m][n], 0, 0, 0);
        __builtin_amdgcn_s_setprio(0);
        if (t + 1 < nt) {
            asm volatile("s_waitcnt vmcnt(0)" ::: "memory");
            __builtin_amdgcn_s_barrier();
            asm volatile("" ::: "memory");
            cur ^= 1;
        }
    }

    #pragma unroll
    for (int n = 0; n < TN; ++n) {
        int col = col0 + wc * (BN / 2) + n * 16 + fr;
        float bb = bias ? bias[col] : 0.f;
        #pragma unroll
        for (int m = 0; m < TM; ++m) {
            int rbase = row0 + wr * (BM / 2) + m * 16 + fc * 4;
            #pragma unroll
            for (int rr = 0; rr < 4; ++rr) {
                float x = acc[m][n][rr] + bb;
                if constexpr (ACT) x = fmaxf(x, 0.f);
                long long ci = (long long)(rbase + rr) * ldc + col;
                if constexpr (CMODE == 0) Cf[ci] = x;
                else                      Cb[ci] = (bf16)x;
            }
        }
    }
}

// VT[h][d][s] = qkv[s][1024 + h*64 + d]   (bf16 64x64 LDS transpose)
__global__ __launch_bounds__(256)
void vt_k(const bf16* __restrict__ qkv, bf16* __restrict__ VT)
{
    __shared__ bf16 t[64][80];
    int h = blockIdx.y, s0 = blockIdx.x * 64;
    int r = threadIdx.x >> 2, c16 = (threadIdx.x & 3) * 16;
    const bf16* src = qkv + (long long)(s0 + r) * 1536 + 1024 + h * 64 + c16;
    *(bf16x8*)&t[r][c16]     = *(const bf16x8*)src;
    *(bf16x8*)&t[r][c16 + 8] = *(const bf16x8*)(src + 8);
    __syncthreads();
    int d = r, seg = c16;
    bf16 tmp[16];
    #pragma unroll
    for (int j = 0; j < 16; ++j) tmp[j] = t[seg + j][d];
    bf16* dst = VT + ((long long)(h * 64 + d)) * 512 + s0 + seg;
    *(bf16x8*)dst       = *(bf16x8*)&tmp[0];
    *(bf16x8*)(dst + 8) = *(bf16x8*)&tmp[8];
}

// x[row] = LN(x[row] + res[row & mask]) ; 2 rows per 256-thread block
__global__ __launch_bounds__(256)
void addln_k(bf16* __restrict__ xb, const bf16* __restrict__ res,
             unsigned resMask, const float* __restrict__ g,
             const float* __restrict__ bta)
{
    const int tid = threadIdx.x;
    const int sub = tid >> 7;
    const long long row = (long long)blockIdx.x * 2 + sub;
    const int lt = tid & 127;
    const int c = lt * 4;
    bf16x4 xv4 = *(const bf16x4*)&xb[row * 512 + c];
    bf16x4 rv4 = *(const bf16x4*)&res[(long long)(row & resMask) * 512 + c];
    float x0 = (float)xv4[0] + (float)rv4[0];
    float x1 = (float)xv4[1] + (float)rv4[1];
    float x2 = (float)xv4[2] + (float)rv4[2];
    float x3 = (float)xv4[3] + (float)rv4[3];
    float s = x0 + x1 + x2 + x3;
    float qq = x0 * x0 + x1 * x1 + x2 * x2 + x3 * x3;
    #pragma unroll
    for (int off = 32; off; off >>= 1) {
        s += __shfl_xor(s, off);
        qq += __shfl_xor(qq, off);
    }
    __shared__ float rs[4], rq[4];
    if ((tid & 63) == 0) { rs[tid >> 6] = s; rq[tid >> 6] = qq; }
    __syncthreads();
    s = rs[sub * 2] + rs[sub * 2 + 1];
    qq = rq[sub * 2] + rq[sub * 2 + 1];
    float mean = s * (1.0f / 512.0f);
    float var  = qq * (1.0f / 512.0f) - mean * mean;
    float rstd = rsqrtf(var + 1e-5f);
    float4 gv = *(const float4*)&g[c];
    float4 bv = *(const float4*)&bta[c];
    bf16x4 o4;
    o4[0] = (bf16)((x0 - mean) * rstd * gv.x + bv.x);
    o4[1] = (bf16)((x1 - mean) * rstd * gv.y + bv.y);
    o4[2] = (bf16)((x2 - mean) * rstd * gv.z + bv.z);
    o4[3] = (bf16)((x3 - mean) * rstd * gv.w + bv.w);
    *(bf16x4*)&xb[row * 512 + c] = o4;
}

// out[row] = dot(x[row,:], fcW) + fcb   (x bf16)
__global__ __launch_bounds__(256)
void fc_k(const bf16* __restrict__ x, const float* __restrict__ w,
          const float* __restrict__ bb, float* __restrict__ out)
{
    int row  = blockIdx.x * 4 + (threadIdx.x >> 6);
    int lane = threadIdx.x & 63;
    const bf16* xr = x + (long long)row * 512;
    bf16x8 a8 = *(const bf16x8*)&xr[lane * 8];
    float4 w0 = *(const float4*)&w[lane * 8];
    float4 w1 = *(const float4*)&w[lane * 8 + 4];
    float s = (float)a8[0] * w0.x + (float)a8[1] * w0.y
            + (float)a8[2] * w0.z + (float)a8[3] * w0.w
            + (float)a8[4] * w1.x + (float)a8[5] * w1.y
            + (float)a8[6] * w1.z + (float)a8[7] * w1.w;
    #pragma unroll
    for (int off = 32; off; off >>= 1) s += __shfl_xor(s, off);
    if (lane == 0) out[row] = s + bb[0];
}

extern "C" void kernel_launch(void* const* d_in, const int* in_sizes, int n_in,
                              void* d_out, int out_size, void* d_ws, size_t ws_size,
                              hipStream_t stream)
{
    const float* input_seq = (const float*)d_in[0];
    const float* emb_W  = (const float*)d_in[1];
    const float* emb_b  = (const float*)d_in[2];
    const float* pos_emb= (const float*)d_in[3];
    const float* Wq = (const float*)d_in[4];
    const float* bq = (const float*)d_in[5];
    const float* Wk = (const float*)d_in[6];
    const float* bk = (const float*)d_in[7];
    const float* Wv = (const float*)d_in[8];
    const float* bv = (const float*)d_in[9];
    const float* Wo = (const float*)d_in[10];
    const float* bo = (const float*)d_in[11];
    const float* ln1_g = (const float*)d_in[12];
    const float* ln1_b = (const float*)d_in[13];
    const float* W1 = (const float*)d_in[14];
    const float* b1 = (const float*)d_in[15];
    const float* W2 = (const float*)d_in[16];
    const float* b2 = (const float*)d_in[17];
    const float* ln2_g = (const float*)d_in[18];
    const float* ln2_b = (const float*)d_in[19];
    const float* fcW = (const float*)d_in[20];
    const float* fcb = (const float*)d_in[21];
    float* out = (float*)d_out;

    // ---- workspace layout ----
    char* w = (char*)d_ws;
    size_t off = 0;
    auto alloc = [&](size_t bytes) -> void* {
        off = (off + 255) & ~(size_t)255;
        void* p = w + off;
        off += bytes;
        return p;
    };
    bf16*  xb     = (bf16*) alloc(16384ull * 512 * 2);   // 16 MB
    bf16*  embWT  = (bf16*) alloc(512ull * 2048 * 2);
    bf16*  qkvWT  = (bf16*) alloc(2ull * 1536 * 512 * 2);
    bf16*  WoT    = (bf16*) alloc(2ull * 512 * 512 * 2);
    bf16*  W1T    = (bf16*) alloc(2ull * 2048 * 512 * 2);
    bf16*  W2T    = (bf16*) alloc(2ull * 512 * 2048 * 2);
    float* qkvB   = (float*)alloc(2ull * 1536 * 4);
    off = (off + 255) & ~(size_t)255;
    char* dynp = w + off;
    // overlay A (attention phase): qkv + VT + attn outputs (~3 MB)
    bf16*  qkv      = (bf16*)dynp;                         // 512x1536
    bf16*  VT       = (bf16*)(dynp + 1572864);             // 512x512
    bf16*  attn0b   = (bf16*)(dynp + 1572864 + 524288);    // 512x512
    bf16*  attnout0b= (bf16*)(dynp + 1572864 + 524288 + 524288);
    // overlay B (FFN phase): hidden bf16 [16384][2048] + ffout bf16 [16384][512]
    bf16*  hidden = (bf16*)dynp;                           // 67 MB
    bf16*  ffout  = (bf16*)(dynp + 16384ull * 2048 * 2);   // 16 MB

    dim3 blk(256);
    dim3 blk512(512);

    // ---- preprocessing: weight transposes + bias packs ----
    prep_k<<<dim3(7170), blk, 0, stream>>>(
        emb_W, embWT, Wq, Wk, Wv, Wo, W1, W2,
        qkvWT, WoT, W1T, W2T, bq, bk, bv, qkvB);

    // ---- embedding: xb = input_seq(f32) @ emb_W + emb_b + pos_emb ----
    mg8f<<<dim3(4, 64), blk512, 0, stream>>>(
        input_seq, 2048, embWT, 2048, emb_b, pos_emb, xb, 512, 2048);

    for (int l = 0; l < 2; ++l) {
        const bf16* qkvWT_l = qkvWT + l * 786432;
        const bf16* WoT_l   = WoT + l * 262144;
        const bf16* W1T_l   = W1T + l * 1048576;
        const bf16* W2T_l   = W2T + l * 1048576;

        // QKV projection (batch 0 rows only), packed N=1536, bf16 out
        mgemm<128, 64, 0, 1, 0><<<dim3(24, 4), blk, 0, stream>>>(
            xb, 512, 0, qkvWT_l, 512, 0, qkvB + l * 1536,
            nullptr, qkv, 1536, 0, 512);
        // V transpose for the fused attention's B-operand
        vt_k<<<dim3(8, 8), blk, 0, stream>>>(qkv, VT);
        // fused QK^T + masked softmax + PV (64 blocks x 4 waves)
        fattn<<<dim3(8, 8), blk, 0, stream>>>(qkv, VT, attn0b);
        // attnout0 = attn0 @ Wo + bo, bf16 out
        mgemm<128, 64, 0, 1, 0><<<dim3(8, 4), blk, 0, stream>>>(
            attn0b, 512, 0, WoT_l, 512, 0, bo + l * 512, nullptr,
            attnout0b, 512, 0, 512);
        // x = LN1(x + attnout0[s]) broadcast
        addln_k<<<dim3(8192), blk, 0, stream>>>(
            xb, attnout0b, 511u, ln1_g + l * 512, ln1_b + l * 512);

        // ---- FFN (full, unchunked) ----
        mg8<256, 1><<<dim3(8, 64), blk512, 0, stream>>>(
            xb, 512, W1T_l, 512, b1 + l * 2048, hidden, 2048, 512);
        mg8<128, 0><<<dim3(4, 64), blk512, 0, stream>>>(
            hidden, 2048, W2T_l, 2048, b2 + l * 512, ffout, 512, 2048);
        addln_k<<<dim3(8192), blk, 0, stream>>>(
            xb, ffout, 0xffffffffu, ln2_g + l * 512, ln2_b + l * 512);
    }

    // ---- out = x @ fc_W + fc_b ----
    fc_k<<<dim3(4096), blk, 0, stream>>>(xb, fcW, fcb, out);
}

// Round 19
// 347.165 us; speedup vs baseline: 1.1192x; 1.0107x over previous
//
#include <hip/hip_runtime.h>

// SASRec forward, bf16-MFMA. Round 19 (= round 18/16 + LDS bank-conflict fix):
//  - All [row][64B] LDS tiles (mg8 A+B, mgemm A+B, mg8f B) switch the chunk
//    involution from fc^(row&3) to fc^((row>>1)&3): 16-lane fragment reads
//    spread over 8 bank-quads (2-way, free) instead of 4 (4-way, 1.58x).
//    Applied to BOTH the staging-source pre-swizzle and the read offsets
//    (same involution -> correctness unchanged).
//  - mg8f A (128B rows, row&7 XOR) already 2-way; fattn untouched.
// Faithful-bug 1: attention computed for batch 0 only (attn[0] broadcast).
// Faithful-bug 2: tril-then-scale with zeros (not -inf); softmax over full row.

typedef __bf16 bf16;
typedef __bf16 bf16x8 __attribute__((ext_vector_type(8)));
typedef __bf16 bf16x4 __attribute__((ext_vector_type(4)));
typedef float  f32x4  __attribute__((ext_vector_type(4)));

#define SEQ 512

__device__ __forceinline__ void gl2lds16(const void* g, void* l) {
    __builtin_amdgcn_global_load_lds(
        (const __attribute__((address_space(1))) void*)g,
        (__attribute__((address_space(3))) void*)l, 16, 0, 0);
}

template<int N> __device__ __forceinline__ void waitvm() {
    if constexpr (N == 0)       asm volatile("s_waitcnt vmcnt(0)" ::: "memory");
    else if constexpr (N == 2)  asm volatile("s_waitcnt vmcnt(2)" ::: "memory");
    else if constexpr (N == 3)  asm volatile("s_waitcnt vmcnt(3)" ::: "memory");
    else if constexpr (N == 4)  asm volatile("s_waitcnt vmcnt(4)" ::: "memory");
    else if constexpr (N == 5)  asm volatile("s_waitcnt vmcnt(5)" ::: "memory");
    else if constexpr (N == 6)  asm volatile("s_waitcnt vmcnt(6)" ::: "memory");
    else if constexpr (N == 8)  asm volatile("s_waitcnt vmcnt(8)" ::: "memory");
    else if constexpr (N == 9)  asm volatile("s_waitcnt vmcnt(9)" ::: "memory");
    else if constexpr (N == 10) asm volatile("s_waitcnt vmcnt(10)" ::: "memory");
    else static_assert(N == 0, "unsupported waitvm");
}

// swizzle for 64B-row tiles: chunk ^= (row>>1)&3   (2-way bank spread)
__device__ __forceinline__ int swz4(int row) { return (row >> 1) & 3; }

// ============================================================================
// prep_k: 7168 weight-transpose tiles (static decode) + 2 qkv bias packs.
// ============================================================================
__global__ __launch_bounds__(256)
void prep_k(const float* __restrict__ emb_W, bf16* __restrict__ embWT,
            const float* __restrict__ Wq, const float* __restrict__ Wk,
            const float* __restrict__ Wv, const float* __restrict__ Wo,
            const float* __restrict__ W1, const float* __restrict__ W2,
            bf16* __restrict__ qkvWT, bf16* __restrict__ WoT,
            bf16* __restrict__ W1T, bf16* __restrict__ W2T,
            const float* __restrict__ bq, const float* __restrict__ bk,
            const float* __restrict__ bv, float* __restrict__ qkvB)
{
    const int b = blockIdx.x;
    if (b < 7168) {
        const float* src;
        bf16* dst;
        int K, N, t;
        if (b < 1024) {
            src = emb_W; dst = embWT; K = 2048; N = 512; t = b;
        } else {
            const int bb = b - 1024;
            const int l = bb >= 3072 ? 1 : 0;
            const int r = bb - l * 3072;
            if (r < 256)       { src = Wq + l * 262144;  dst = qkvWT + l * 786432;          K = 512;  N = 512;  t = r; }
            else if (r < 512)  { src = Wk + l * 262144;  dst = qkvWT + l * 786432 + 262144; K = 512;  N = 512;  t = r - 256; }
            else if (r < 768)  { src = Wv + l * 262144;  dst = qkvWT + l * 786432 + 524288; K = 512;  N = 512;  t = r - 512; }
            else if (r < 1024) { src = Wo + l * 262144;  dst = WoT + l * 262144;            K = 512;  N = 512;  t = r - 768; }
            else if (r < 2048) { src = W1 + l * 1048576; dst = W1T + l * 1048576;           K = 512;  N = 2048; t = r - 1024; }
            else               { src = W2 + l * 1048576; dst = W2T + l * 1048576;           K = 2048; N = 512;  t = r - 2048; }
        }
        const int tx = N >> 5;
        const int n0 = (t % tx) * 32, k0 = (t / tx) * 32;
        __shared__ float tl[32][33];
        int r2 = threadIdx.x >> 3, c4 = (threadIdx.x & 7) * 4;
        float4 v = *(const float4*)&src[(long long)(k0 + r2) * N + n0 + c4];
        tl[r2][c4 + 0] = v.x; tl[r2][c4 + 1] = v.y;
        tl[r2][c4 + 2] = v.z; tl[r2][c4 + 3] = v.w;
        __syncthreads();
        int n = threadIdx.x >> 3, kk4 = (threadIdx.x & 7) * 4;
        bf16x4 o;
        o[0] = (bf16)tl[kk4 + 0][n]; o[1] = (bf16)tl[kk4 + 1][n];
        o[2] = (bf16)tl[kk4 + 2][n]; o[3] = (bf16)tl[kk4 + 3][n];
        *(bf16x4*)&dst[(long long)(n0 + n) * K + k0 + kk4] = o;
    } else {
        const int l = b - 7168;
        for (int t2 = threadIdx.x; t2 < 512; t2 += 256) {
            qkvB[l * 1536 + t2]        = bq[l * 512 + t2];
            qkvB[l * 1536 + 512 + t2]  = bk[l * 512 + t2];
            qkvB[l * 1536 + 1024 + t2] = bv[l * 512 + t2];
        }
    }
}

// ============================================================================
// mg8f: Cb = A(f32) @ Bt^T + bias + pos. BM=256, BN=128, BK=64, 160 KB LDS.
// A: 128B rows, chunk^(row&7) (2-way, unchanged). B: 64B rows, swz4 (NEW).
// ============================================================================
__global__ __launch_bounds__(512, 1)
void mg8f(const float* __restrict__ Af, int lda,
          const bf16* __restrict__ Bt, int ldb,
          const float* __restrict__ bias, const float* __restrict__ pos,
          bf16* __restrict__ Cb, int ldc, int K)
{
    constexpr int BM = 256, BN = 128;
    constexpr int APASS = 4;
    constexpr int BPASS = 1;
    constexpr int AHB = BM * 32 * 4;      // 32768 B (f32)
    constexpr int BHB = BN * 64;          // 8192 B (bf16)
    constexpr int WM = 4, WN = 2;
    constexpr int MR = BM / WM / 16;      // 4
    constexpr int NR = BN / WN / 16;      // 4
    __shared__ __align__(1024) char smem[4 * AHB + 4 * BHB];   // 160 KB
    char* ABase = smem;
    char* BBase = smem + 4 * AHB;

    const int gx = gridDim.x, gy = gridDim.y;
    const int nwg = gx * gy;
    const int b = blockIdx.y * gx + blockIdx.x;
    const int q = nwg >> 3, r = nwg & 7;
    const int xcd = b & 7, loc = b >> 3;
    const int wg = (xcd < r ? xcd * (q + 1) : r * (q + 1) + (xcd - r) * q) + loc;
    const int bx = wg % gx, by = wg / gx;
    const int row0 = by * BM, col0 = bx * BN;

    const int tid = threadIdx.x, lane = tid & 63, wv = tid >> 6;
    const int wr = wv >> 1, wc = wv & 1;
    const int fr = lane & 15, fc = lane >> 4;

    const float* aS[APASS];
    #pragma unroll
    for (int p = 0; p < APASS; ++p) {
        int cL = p * 512 + tid;
        int row = cL >> 3, ch = cL & 7;
        aS[p] = Af + (long long)(row0 + row) * lda + ((ch ^ (row & 7)) * 4);
    }
    const bf16* bS0;
    {
        int cL = tid;
        int row = cL >> 2, ch = cL & 3;
        bS0 = Bt + (long long)(col0 + row) * ldb + ((ch ^ swz4(row)) * 8);
    }
    int aOff0[MR], aOff1[MR];
    #pragma unroll
    for (int m = 0; m < MR; ++m) {
        int row = wr * (BM / WM) + m * 16 + fr;
        aOff0[m] = row * 128 + (((2 * fc)     ^ (row & 7)) * 16);
        aOff1[m] = row * 128 + (((2 * fc + 1) ^ (row & 7)) * 16);
    }
    int bOff[NR];
    #pragma unroll
    for (int n = 0; n < NR; ++n) {
        int row = wc * (BN / WN) + n * 16 + fr;
        bOff[n] = row * 64 + ((fc ^ swz4(row)) * 16);
    }

    auto stagePart = [&](int j) {
        const int tau = j >> 2, kh = (j >> 1) & 1, d = tau & 1;
        const int koff = tau * 64 + kh * 32;
        if (!(j & 1)) {
            char* dst = ABase + (d * 2 + kh) * AHB + wv * 1024;
            #pragma unroll
            for (int p = 0; p < APASS; ++p)
                gl2lds16(aS[p] + koff, dst + p * 8192);
        } else {
            char* dst = BBase + (d * 2 + kh) * BHB + wv * 1024;
            gl2lds16(bS0 + koff, dst);
        }
    };

    const int nt = K >> 6;
    const int T = 4 * nt;
    #pragma unroll
    for (int j = 0; j < 6; ++j)
        if (j < T) stagePart(j);
    waitvm<2 * (APASS + BPASS)>();
    __builtin_amdgcn_s_barrier();

    f32x4 acc[MR][NR] = {};
    const int NPH = 2 * nt;
    for (int g = 0; g < NPH; ++g) {
        const int tau = g >> 1, ks = g & 1, d = tau & 1;

        const char* as = ABase + (d * 2 + ks) * AHB;
        const char* bs = BBase + (d * 2 + ks) * BHB;
        bf16x8 a[MR], b2[NR];
        #pragma unroll
        for (int m = 0; m < MR; ++m) {
            f32x4 lo = *(const f32x4*)(as + aOff0[m]);
            f32x4 hi = *(const f32x4*)(as + aOff1[m]);
            bf16x8 w8;
            w8[0] = (bf16)lo[0]; w8[1] = (bf16)lo[1];
            w8[2] = (bf16)lo[2]; w8[3] = (bf16)lo[3];
            w8[4] = (bf16)hi[0]; w8[5] = (bf16)hi[1];
            w8[6] = (bf16)hi[2]; w8[7] = (bf16)hi[3];
            a[m] = w8;
        }
        #pragma unroll
        for (int n = 0; n < NR; ++n) b2[n] = *(const bf16x8*)(bs + bOff[n]);

        if (2 * g + 6 < T) stagePart(2 * g + 6);
        if (2 * g + 7 < T) stagePart(2 * g + 7);

        __builtin_amdgcn_s_setprio(1);
        #pragma unroll
        for (int m = 0; m < MR; ++m)
            #pragma unroll
            for (int n = 0; n < NR; ++n)
                acc[m][n] = __builtin_amdgcn_mfma_f32_16x16x32_bf16(
                    a[m], b2[n], acc[m][n], 0, 0, 0);
        __builtin_amdgcn_s_setprio(0);

        const int rem = T - (2 * g + 4);
        if (rem >= 4)      waitvm<2 * (APASS + BPASS)>();
        else if (rem == 3) waitvm<2 * APASS + BPASS>();
        else if (rem == 2) waitvm<APASS + BPASS>();
        else if (rem == 1) waitvm<APASS>();
        else               waitvm<0>();
        __builtin_amdgcn_s_barrier();
    }

    float* st = (float*)(smem + wv * 4096);
    const int rowb = row0 + wr * (BM / WM);
    const int colb = col0 + wc * (BN / WN);
    #pragma unroll
    for (int m = 0; m < MR; ++m) {
        #pragma unroll
        for (int n = 0; n < NR; ++n) {
            int col = colb + n * 16 + fr;
            float bb = bias ? bias[col] : 0.f;
            #pragma unroll
            for (int rr = 0; rr < 4; ++rr) {
                float x = acc[m][n][rr] + bb;
                int rowg = rowb + m * 16 + fc * 4 + rr;
                x += pos[(rowg & 511) * 512 + col];
                st[(fc * 4 + rr) * 64 + n * 16 + fr] = x;
            }
        }
        #pragma unroll
        for (int sgi = 0; sgi < 2; ++sgi) {
            int row = sgi * 8 + (lane >> 3);
            int c8 = (lane & 7) * 8;
            f32x4 u = *(const f32x4*)&st[row * 64 + c8];
            f32x4 v = *(const f32x4*)&st[row * 64 + c8 + 4];
            bf16x8 w8;
            w8[0] = (bf16)u[0]; w8[1] = (bf16)u[1];
            w8[2] = (bf16)u[2]; w8[3] = (bf16)u[3];
            w8[4] = (bf16)v[0]; w8[5] = (bf16)v[1];
            w8[6] = (bf16)v[2]; w8[7] = (bf16)v[3];
            *(bf16x8*)&Cb[(long long)(rowb + m * 16 + row) * ldc + colb + c8] = w8;
        }
    }
}

// ============================================================================
// fattn: fused attention for batch 0 (verified rounds 15-18, untouched)
// ============================================================================
__global__ __launch_bounds__(256, 1)
void fattn(const bf16* __restrict__ qkv,   // [512][1536] (Q|K|V per layer)
           const bf16* __restrict__ VT,    // [8*64][512]
           bf16* __restrict__ attn0b)      // [512][512]
{
    __shared__ __align__(1024) char smem[65536 + 65536 + 4096];
    char* Ks = smem;
    char* Vs = smem + 65536;
    const int h = blockIdx.y;
    const int q0 = blockIdx.x * 64;
    const int tid = threadIdx.x, lane = tid & 63, wv = tid >> 6;
    const int fr = lane & 15, fc = lane >> 4;
    char* Ps = smem + 131072 + wv * 1024;

    {
        const bf16* Kg = qkv + 512 + h * 64;
        #pragma unroll
        for (int p = 0; p < 16; ++p) {
            int row = p * 32 + (tid >> 3);
            int ch  = tid & 7;
            gl2lds16(Kg + (long long)row * 1536 + ((ch ^ (row & 7)) * 8),
                     Ks + p * 4096 + tid * 16);
        }
        const bf16* Vg = VT + (long long)h * 64 * 512;
        #pragma unroll
        for (int p = 0; p < 16; ++p) {
            int row = p * 4 + (tid >> 6);
            int ch  = tid & 63;
            int chg = (ch & ~7) | ((ch & 7) ^ (row & 7));
            gl2lds16(Vg + (long long)row * 512 + chg * 8,
                     Vs + p * 4096 + tid * 16);
        }
    }
    const int q0w = q0 + wv * 16;
    const int qg  = q0w + fr;
    bf16x8 qf[2];
    #pragma unroll
    for (int w = 0; w < 2; ++w)
        qf[w] = *(const bf16x8*)(qkv + (long long)qg * 1536 + h * 64 + w * 32 + fc * 8);

    asm volatile("s_waitcnt vmcnt(0)" ::: "memory");
    __builtin_amdgcn_s_barrier();
    asm volatile("" ::: "memory");

    f32x4 s[32] = {};
    #pragma unroll
    for (int kt = 0; kt < 32; ++kt) {
        #pragma unroll
        for (int w = 0; w < 2; ++w) {
            int row = kt * 16 + fr;
            bf16x8 kf = *(const bf16x8*)(Ks + row * 128 +
                                         (((w * 4 + fc) ^ (row & 7)) * 16));
            s[kt] = __builtin_amdgcn_mfma_f32_16x16x32_bf16(kf, qf[w], s[kt], 0, 0, 0);
        }
    }

    float mx = -3.4e38f;
    #pragma unroll
    for (int kt = 0; kt < 32; ++kt)
        #pragma unroll
        for (int rr = 0; rr < 4; ++rr) {
            int k = kt * 16 + fc * 4 + rr;
            float v = (k <= qg) ? s[kt][rr] * 0.125f : 0.0f;
            s[kt][rr] = v;
            mx = fmaxf(mx, v);
        }
    mx = fmaxf(mx, __shfl_xor(mx, 16));
    mx = fmaxf(mx, __shfl_xor(mx, 32));
    float sum = 0.f;
    #pragma unroll
    for (int kt = 0; kt < 32; ++kt)
        #pragma unroll
        for (int rr = 0; rr < 4; ++rr) {
            float e = __expf(s[kt][rr] - mx);
            s[kt][rr] = e;
            sum += e;
        }
    sum += __shfl_xor(sum, 16);
    sum += __shfl_xor(sum, 32);
    const float inv = 1.0f / sum;

    f32x4 o[4] = {};
    #pragma unroll
    for (int kt2 = 0; kt2 < 16; ++kt2) {
        bf16x4 u0, u1;
        #pragma unroll
        for (int rr = 0; rr < 4; ++rr) {
            u0[rr] = (bf16)(s[2 * kt2][rr] * inv);
            u1[rr] = (bf16)(s[2 * kt2 + 1][rr] * inv);
        }
        *(bf16x4*)(Ps + fr * 64 + ((fc ^ (fr & 7)) * 8))       = u0;
        *(bf16x4*)(Ps + fr * 64 + (((4 + fc) ^ (fr & 7)) * 8)) = u1;
        __threadfence_block();
        bf16x4 lo = *(const bf16x4*)(Ps + fr * 64 + (((2 * fc) ^ (fr & 7)) * 8));
        bf16x4 hi = *(const bf16x4*)(Ps + fr * 64 + (((2 * fc + 1) ^ (fr & 7)) * 8));
        bf16x8 pf;
        pf[0] = lo[0]; pf[1] = lo[1]; pf[2] = lo[2]; pf[3] = lo[3];
        pf[4] = hi[0]; pf[5] = hi[1]; pf[6] = hi[2]; pf[7] = hi[3];
        #pragma unroll
        for (int n = 0; n < 4; ++n) {
            int row = n * 16 + fr;
            int ch  = kt2 * 4 + fc;
            int chs = (ch & ~7) | ((ch & 7) ^ (row & 7));
            bf16x8 vf = *(const bf16x8*)(Vs + row * 1024 + chs * 16);
            o[n] = __builtin_amdgcn_mfma_f32_16x16x32_bf16(pf, vf, o[n], 0, 0, 0);
        }
    }

    #pragma unroll
    for (int n = 0; n < 4; ++n)
        #pragma unroll
        for (int rr = 0; rr < 4; ++rr) {
            int qrow = q0w + fc * 4 + rr;
            attn0b[(long long)qrow * 512 + h * 64 + n * 16 + fr] = (bf16)o[n][rr];
        }
}

// ============================================================================
// mg8: Cb = act(A @ Bt^T + bias) bf16 A; 64B rows now swz4 both sides.
// ============================================================================
template<int BN, int ACT>
__global__ __launch_bounds__(512, 1)
void mg8(const bf16* __restrict__ Ab, int lda,
         const bf16* __restrict__ Bt, int ldb,
         const float* __restrict__ bias,
         bf16* __restrict__ Cb, int ldc, int K)
{
    constexpr int BM = 256;
    constexpr int APASS = 2;
    constexpr int BPASS = BN / 128;
    constexpr int AHB = BM * 64;
    constexpr int BHB = BN * 64;
    constexpr int WM = (BN == 256 ? 2 : 4), WN = 8 / WM;
    constexpr int MR = BM / WM / 16;
    constexpr int NR = BN / WN / 16;
    __shared__ __align__(1024) char smem[4 * AHB + 4 * BHB];
    char* ABase = smem;
    char* BBase = smem + 4 * AHB;

    const int gx = gridDim.x, gy = gridDim.y;
    const int nwg = gx * gy;
    const int b = blockIdx.y * gx + blockIdx.x;
    const int q = nwg >> 3, r = nwg & 7;
    const int xcd = b & 7, loc = b >> 3;
    const int wg = (xcd < r ? xcd * (q + 1) : r * (q + 1) + (xcd - r) * q) + loc;
    const int bx = wg % gx, by = wg / gx;
    const int row0 = by * BM, col0 = bx * BN;

    const int tid = threadIdx.x, lane = tid & 63, wv = tid >> 6;
    const int wr = (WM == 2 ? (wv >> 2) : (wv >> 1));
    const int wc = (WM == 2 ? (wv & 3) : (wv & 1));
    const int fr = lane & 15, fc = lane >> 4;

    const bf16* aS[APASS];
    #pragma unroll
    for (int p = 0; p < APASS; ++p) {
        int cL = p * 512 + tid;
        int row = cL >> 2, ch = cL & 3;
        aS[p] = Ab + (long long)(row0 + row) * lda + ((ch ^ swz4(row)) * 8);
    }
    const bf16* bS[BPASS];
    #pragma unroll
    for (int p = 0; p < BPASS; ++p) {
        int cL = p * 512 + tid;
        int row = cL >> 2, ch = cL & 3;
        bS[p] = Bt + (long long)(col0 + row) * ldb + ((ch ^ swz4(row)) * 8);
    }
    int aOff[MR], bOff[NR];
    #pragma unroll
    for (int m = 0; m < MR; ++m) {
        int row = wr * (BM / WM) + m * 16 + fr;
        aOff[m] = row * 64 + ((fc ^ swz4(row)) * 16);
    }
    #pragma unroll
    for (int n = 0; n < NR; ++n) {
        int row = wc * (BN / WN) + n * 16 + fr;
        bOff[n] = row * 64 + ((fc ^ swz4(row)) * 16);
    }

    auto stagePart = [&](int j) {
        const int tau = j >> 2, kh = (j >> 1) & 1, d = tau & 1;
        const int koff = tau * 64 + kh * 32;
        if (!(j & 1)) {
            char* dst = ABase + (d * 2 + kh) * AHB + wv * 1024;
            #pragma unroll
            for (int p = 0; p < APASS; ++p)
                gl2lds16(aS[p] + koff, dst + p * 8192);
        } else {
            char* dst = BBase + (d * 2 + kh) * BHB + wv * 1024;
            #pragma unroll
            for (int p = 0; p < BPASS; ++p)
                gl2lds16(bS[p] + koff, dst + p * 8192);
        }
    };

    const int nt = K >> 6;
    const int T = 4 * nt;
    #pragma unroll
    for (int j = 0; j < 6; ++j)
        if (j < T) stagePart(j);
    waitvm<2 * (APASS + BPASS)>();
    __builtin_amdgcn_s_barrier();

    f32x4 acc[MR][NR] = {};
    const int NPH = 2 * nt;
    for (int g = 0; g < NPH; ++g) {
        const int tau = g >> 1, ks = g & 1, d = tau & 1;

        const char* as = ABase + (d * 2 + ks) * AHB;
        const char* bs = BBase + (d * 2 + ks) * BHB;
        bf16x8 a[MR], b2[NR];
        #pragma unroll
        for (int m = 0; m < MR; ++m) a[m] = *(const bf16x8*)(as + aOff[m]);
        #pragma unroll
        for (int n = 0; n < NR; ++n) b2[n] = *(const bf16x8*)(bs + bOff[n]);

        if (2 * g + 6 < T) stagePart(2 * g + 6);
        if (2 * g + 7 < T) stagePart(2 * g + 7);

        __builtin_amdgcn_s_setprio(1);
        #pragma unroll
        for (int m = 0; m < MR; ++m)
            #pragma unroll
            for (int n = 0; n < NR; ++n)
                acc[m][n] = __builtin_amdgcn_mfma_f32_16x16x32_bf16(
                    a[m], b2[n], acc[m][n], 0, 0, 0);
        __builtin_amdgcn_s_setprio(0);

        const int rem = T - (2 * g + 4);
        if (rem >= 4)      waitvm<2 * (APASS + BPASS)>();
        else if (rem == 3) waitvm<2 * APASS + BPASS>();
        else if (rem == 2) waitvm<APASS + BPASS>();
        else if (rem == 1) waitvm<APASS>();
        else               waitvm<0>();
        __builtin_amdgcn_s_barrier();
    }

    float* st = (float*)(smem + wv * 4096);
    const int rowb = row0 + wr * (BM / WM);
    const int colb = col0 + wc * (BN / WN);
    #pragma unroll
    for (int m = 0; m < MR; ++m) {
        #pragma unroll
        for (int n = 0; n < NR; ++n) {
            int col = colb + n * 16 + fr;
            float bb = bias ? bias[col] : 0.f;
            #pragma unroll
            for (int rr = 0; rr < 4; ++rr) {
                float x = acc[m][n][rr] + bb;
                if constexpr (ACT) x = fmaxf(x, 0.f);
                st[(fc * 4 + rr) * 64 + n * 16 + fr] = x;
            }
        }
        #pragma unroll
        for (int sgi = 0; sgi < 2; ++sgi) {
            int row = sgi * 8 + (lane >> 3);
            int c8 = (lane & 7) * 8;
            f32x4 u = *(const f32x4*)&st[row * 64 + c8];
            f32x4 v = *(const f32x4*)&st[row * 64 + c8 + 4];
            bf16x8 w8;
            w8[0] = (bf16)u[0]; w8[1] = (bf16)u[1];
            w8[2] = (bf16)u[2]; w8[3] = (bf16)u[3];
            w8[4] = (bf16)v[0]; w8[5] = (bf16)v[1];
            w8[6] = (bf16)v[2]; w8[7] = (bf16)v[3];
            *(bf16x8*)&Cb[(long long)(rowb + m * 16 + row) * ldc + colb + c8] = w8;
        }
    }
}

// ============================================================================
// mgemm: 128x64 2-phase template for the small projection GEMMs (swz4)
// ============================================================================
template<int BM, int BN, int ACT, int CMODE, int CAUSAL>
__global__ __launch_bounds__(256, 4)
void mgemm(const bf16* __restrict__ Ab, int lda, long long sA,
           const bf16* __restrict__ Bt, int ldb, long long sB,
           const float* __restrict__ bias,
           float* __restrict__ Cf, bf16* __restrict__ Cb, int ldc, long long sC,
           int K)
{
    static_assert(BM == 128 && (BN == 128 || BN == 64), "tile");
    const int gx = gridDim.x, gy = gridDim.y;
    const int nwg = gx * gy;
    const int b = blockIdx.y * gx + blockIdx.x;
    const int q = nwg >> 3, r = nwg & 7;
    const int xcd = b & 7, loc = b >> 3;
    const int wg = (xcd < r ? xcd * (q + 1) : r * (q + 1) + (xcd - r) * q) + loc;
    const int bx = wg % gx, by = wg / gx;
    if (CAUSAL && bx * BN > by * BM + (BM - 1)) return;

    constexpr int TM = BM / 32, TN = BN / 32;
    constexpr int AIT = BM / 64, BIT = BN / 64;
    constexpr int ABY = BM * 64;
    constexpr int BBY = BN * 64;
    __shared__ bf16 As[2 * BM * 32];
    __shared__ bf16 Bs[2 * BN * 32];
    char* AsB = (char*)As;
    char* BsB = (char*)Bs;
    const int tid = threadIdx.x;
    const int lane = tid & 63, wv = tid >> 6;
    const int wr = wv >> 1, wc = wv & 1;
    const int fr = lane & 15, fc = lane >> 4;
    const int row0 = by * BM, col0 = bx * BN;
    const int z = blockIdx.z;

    Ab += (long long)z * sA;
    Bt += (long long)z * sB;
    if constexpr (CMODE == 0) Cf += (long long)z * sC;
    else                      Cb += (long long)z * sC;

    f32x4 acc[TM][TN] = {};

    const bf16* aSrc[AIT];
    #pragma unroll
    for (int it = 0; it < AIT; ++it) {
        int cL = it * 256 + tid;
        int row = cL >> 2, ch = cL & 3;
        aSrc[it] = Ab + (long long)(row0 + row) * lda + ((ch ^ swz4(row)) * 8);
    }
    const bf16* bSrc[BIT];
    #pragma unroll
    for (int it = 0; it < BIT; ++it) {
        int cL = it * 256 + tid;
        int row = cL >> 2, ch = cL & 3;
        bSrc[it] = Bt + (long long)(col0 + row) * ldb + ((ch ^ swz4(row)) * 8);
    }
    int aOff[TM], bOff[TN];
    #pragma unroll
    for (int m = 0; m < TM; ++m) {
        int row = wr * (BM / 2) + m * 16 + fr;
        aOff[m] = row * 64 + ((fc ^ swz4(row)) * 16);
    }
    #pragma unroll
    for (int n = 0; n < TN; ++n) {
        int row = wc * (BN / 2) + n * 16 + fr;
        bOff[n] = row * 64 + ((fc ^ swz4(row)) * 16);
    }

    auto stageTo = [&](int buf, int kt) {
        #pragma unroll
        for (int it = 0; it < AIT; ++it)
            gl2lds16(aSrc[it] + kt, AsB + buf * ABY + it * 4096 + wv * 1024);
        #pragma unroll
        for (int it = 0; it < BIT; ++it)
            gl2lds16(bSrc[it] + kt, BsB + buf * BBY + it * 4096 + wv * 1024);
    };

    const int nt = K >> 5;
    stageTo(0, 0);
    asm volatile("s_waitcnt vmcnt(0)" ::: "memory");
    __builtin_amdgcn_s_barrier();
    asm volatile("" ::: "memory");

    int cur = 0;
    for (int t = 0; t < nt; ++t) {
        if (t + 1 < nt) stageTo(cur ^ 1, (t + 1) * 32);
        bf16x8 a[TM], b2[TN];
        #pragma unroll
        for (int m = 0; m < TM; ++m) a[m] = *(const bf16x8*)(AsB + cur * ABY + aOff[m]);
        #pragma unroll
        for (int n = 0; n < TN; ++n) b2[n] = *(const bf16x8*)(BsB + cur * BBY + bOff[n]);
        __builtin_amdgcn_s_setprio(1);
        #pragma unroll
        for (int m = 0; m < TM; ++m)
            #pragma unroll
            for (int n = 0; n < TN; ++n)
                acc[m][n] = __builtin_amdgcn_mfma_f32_16x16x32_bf16(a[m], b2[n], acc[m][n], 0, 0, 0);
        __builtin_amdgcn_s_setprio(0);
        if (t + 1 < nt) {
            asm volatile("s_waitcnt vmcnt(0)" ::: "memory");
            __builtin_amdgcn_s_barrier();
            asm volatile("" ::: "memory");
            cur ^= 1;
        }
    }

    #pragma unroll
    for (int n = 0; n < TN; ++n) {
        int col = col0 + wc * (BN / 2) + n * 16 + fr;
        float bb = bias ? bias[col] : 0.f;
        #pragma unroll
        for (int m = 0; m < TM; ++m) {
            int rbase = row0 + wr * (BM / 2) + m * 16 + fc * 4;
            #pragma unroll
            for (int rr = 0; rr < 4; ++rr) {
                float x = acc[m][n][rr] + bb;
                if constexpr (ACT) x = fmaxf(x, 0.f);
                long long ci = (long long)(rbase + rr) * ldc + col;
                if constexpr (CMODE == 0) Cf[ci] = x;
                else                      Cb[ci] = (bf16)x;
            }
        }
    }
}

// VT[h][d][s] = qkv[s][1024 + h*64 + d]   (bf16 64x64 LDS transpose)
__global__ __launch_bounds__(256)
void vt_k(const bf16* __restrict__ qkv, bf16* __restrict__ VT)
{
    __shared__ bf16 t[64][80];
    int h = blockIdx.y, s0 = blockIdx.x * 64;
    int r = threadIdx.x >> 2, c16 = (threadIdx.x & 3) * 16;
    const bf16* src = qkv + (long long)(s0 + r) * 1536 + 1024 + h * 64 + c16;
    *(bf16x8*)&t[r][c16]     = *(const bf16x8*)src;
    *(bf16x8*)&t[r][c16 + 8] = *(const bf16x8*)(src + 8);
    __syncthreads();
    int d = r, seg = c16;
    bf16 tmp[16];
    #pragma unroll
    for (int j = 0; j < 16; ++j) tmp[j] = t[seg + j][d];
    bf16* dst = VT + ((long long)(h * 64 + d)) * 512 + s0 + seg;
    *(bf16x8*)dst       = *(bf16x8*)&tmp[0];
    *(bf16x8*)(dst + 8) = *(bf16x8*)&tmp[8];
}

// x[row] = LN(x[row] + res[row & mask]) ; 2 rows per 256-thread block
__global__ __launch_bounds__(256)
void addln_k(bf16* __restrict__ xb, const bf16* __restrict__ res,
             unsigned resMask, const float* __restrict__ g,
             const float* __restrict__ bta)
{
    const int tid = threadIdx.x;
    const int sub = tid >> 7;
    const long long row = (long long)blockIdx.x * 2 + sub;
    const int lt = tid & 127;
    const int c = lt * 4;
    bf16x4 xv4 = *(const bf16x4*)&xb[row * 512 + c];
    bf16x4 rv4 = *(const bf16x4*)&res[(long long)(row & resMask) * 512 + c];
    float x0 = (float)xv4[0] + (float)rv4[0];
    float x1 = (float)xv4[1] + (float)rv4[1];
    float x2 = (float)xv4[2] + (float)rv4[2];
    float x3 = (float)xv4[3] + (float)rv4[3];
    float s = x0 + x1 + x2 + x3;
    float qq = x0 * x0 + x1 * x1 + x2 * x2 + x3 * x3;
    #pragma unroll
    for (int off = 32; off; off >>= 1) {
        s += __shfl_xor(s, off);
        qq += __shfl_xor(qq, off);
    }
    __shared__ float rs[4], rq[4];
    if ((tid & 63) == 0) { rs[tid >> 6] = s; rq[tid >> 6] = qq; }
    __syncthreads();
    s = rs[sub * 2] + rs[sub * 2 + 1];
    qq = rq[sub * 2] + rq[sub * 2 + 1];
    float mean = s * (1.0f / 512.0f);
    float var  = qq * (1.0f / 512.0f) - mean * mean;
    float rstd = rsqrtf(var + 1e-5f);
    float4 gv = *(const float4*)&g[c];
    float4 bv = *(const float4*)&bta[c];
    bf16x4 o4;
    o4[0] = (bf16)((x0 - mean) * rstd * gv.x + bv.x);
    o4[1] = (bf16)((x1 - mean) * rstd * gv.y + bv.y);
    o4[2] = (bf16)((x2 - mean) * rstd * gv.z + bv.z);
    o4[3] = (bf16)((x3 - mean) * rstd * gv.w + bv.w);
    *(bf16x4*)&xb[row * 512 + c] = o4;
}

// out[row] = dot(x[row,:], fcW) + fcb   (x bf16)
__global__ __launch_bounds__(256)
void fc_k(const bf16* __restrict__ x, const float* __restrict__ w,
          const float* __restrict__ bb, float* __restrict__ out)
{
    int row  = blockIdx.x * 4 + (threadIdx.x >> 6);
    int lane = threadIdx.x & 63;
    const bf16* xr = x + (long long)row * 512;
    bf16x8 a8 = *(const bf16x8*)&xr[lane * 8];
    float4 w0 = *(const float4*)&w[lane * 8];
    float4 w1 = *(const float4*)&w[lane * 8 + 4];
    float s = (float)a8[0] * w0.x + (float)a8[1] * w0.y
            + (float)a8[2] * w0.z + (float)a8[3] * w0.w
            + (float)a8[4] * w1.x + (float)a8[5] * w1.y
            + (float)a8[6] * w1.z + (float)a8[7] * w1.w;
    #pragma unroll
    for (int off = 32; off; off >>= 1) s += __shfl_xor(s, off);
    if (lane == 0) out[row] = s + bb[0];
}

extern "C" void kernel_launch(void* const* d_in, const int* in_sizes, int n_in,
                              void* d_out, int out_size, void* d_ws, size_t ws_size,
                              hipStream_t stream)
{
    const float* input_seq = (const float*)d_in[0];
    const float* emb_W  = (const float*)d_in[1];
    const float* emb_b  = (const float*)d_in[2];
    const float* pos_emb= (const float*)d_in[3];
    const float* Wq = (const float*)d_in[4];
    const float* bq = (const float*)d_in[5];
    const float* Wk = (const float*)d_in[6];
    const float* bk = (const float*)d_in[7];
    const float* Wv = (const float*)d_in[8];
    const float* bv = (const float*)d_in[9];
    const float* Wo = (const float*)d_in[10];
    const float* bo = (const float*)d_in[11];
    const float* ln1_g = (const float*)d_in[12];
    const float* ln1_b = (const float*)d_in[13];
    const float* W1 = (const float*)d_in[14];
    const float* b1 = (const float*)d_in[15];
    const float* W2 = (const float*)d_in[16];
    const float* b2 = (const float*)d_in[17];
    const float* ln2_g = (const float*)d_in[18];
    const float* ln2_b = (const float*)d_in[19];
    const float* fcW = (const float*)d_in[20];
    const float* fcb = (const float*)d_in[21];
    float* out = (float*)d_out;

    // ---- workspace layout ----
    char* w = (char*)d_ws;
    size_t off = 0;
    auto alloc = [&](size_t bytes) -> void* {
        off = (off + 255) & ~(size_t)255;
        void* p = w + off;
        off += bytes;
        return p;
    };
    bf16*  xb     = (bf16*) alloc(16384ull * 512 * 2);   // 16 MB
    bf16*  embWT  = (bf16*) alloc(512ull * 2048 * 2);
    bf16*  qkvWT  = (bf16*) alloc(2ull * 1536 * 512 * 2);
    bf16*  WoT    = (bf16*) alloc(2ull * 512 * 512 * 2);
    bf16*  W1T    = (bf16*) alloc(2ull * 2048 * 512 * 2);
    bf16*  W2T    = (bf16*) alloc(2ull * 512 * 2048 * 2);
    float* qkvB   = (float*)alloc(2ull * 1536 * 4);
    off = (off + 255) & ~(size_t)255;
    char* dynp = w + off;
    // overlay A (attention phase): qkv + VT + attn outputs (~3 MB)
    bf16*  qkv      = (bf16*)dynp;                         // 512x1536
    bf16*  VT       = (bf16*)(dynp + 1572864);             // 512x512
    bf16*  attn0b   = (bf16*)(dynp + 1572864 + 524288);    // 512x512
    bf16*  attnout0b= (bf16*)(dynp + 1572864 + 524288 + 524288);
    // overlay B (FFN phase): hidden bf16 [16384][2048] + ffout bf16 [16384][512]
    bf16*  hidden = (bf16*)dynp;                           // 67 MB
    bf16*  ffout  = (bf16*)(dynp + 16384ull * 2048 * 2);   // 16 MB

    dim3 blk(256);
    dim3 blk512(512);

    // ---- preprocessing: weight transposes + bias packs ----
    prep_k<<<dim3(7170), blk, 0, stream>>>(
        emb_W, embWT, Wq, Wk, Wv, Wo, W1, W2,
        qkvWT, WoT, W1T, W2T, bq, bk, bv, qkvB);

    // ---- embedding: xb = input_seq(f32) @ emb_W + emb_b + pos_emb ----
    mg8f<<<dim3(4, 64), blk512, 0, stream>>>(
        input_seq, 2048, embWT, 2048, emb_b, pos_emb, xb, 512, 2048);

    for (int l = 0; l < 2; ++l) {
        const bf16* qkvWT_l = qkvWT + l * 786432;
        const bf16* WoT_l   = WoT + l * 262144;
        const bf16* W1T_l   = W1T + l * 1048576;
        const bf16* W2T_l   = W2T + l * 1048576;

        // QKV projection (batch 0 rows only), packed N=1536, bf16 out
        mgemm<128, 64, 0, 1, 0><<<dim3(24, 4), blk, 0, stream>>>(
            xb, 512, 0, qkvWT_l, 512, 0, qkvB + l * 1536,
            nullptr, qkv, 1536, 0, 512);
        // V transpose for the fused attention's B-operand
        vt_k<<<dim3(8, 8), blk, 0, stream>>>(qkv, VT);
        // fused QK^T + masked softmax + PV (64 blocks x 4 waves)
        fattn<<<dim3(8, 8), blk, 0, stream>>>(qkv, VT, attn0b);
        // attnout0 = attn0 @ Wo + bo, bf16 out
        mgemm<128, 64, 0, 1, 0><<<dim3(8, 4), blk, 0, stream>>>(
            attn0b, 512, 0, WoT_l, 512, 0, bo + l * 512, nullptr,
            attnout0b, 512, 0, 512);
        // x = LN1(x + attnout0[s]) broadcast
        addln_k<<<dim3(8192), blk, 0, stream>>>(
            xb, attnout0b, 511u, ln1_g + l * 512, ln1_b + l * 512);

        // ---- FFN (full, unchunked) ----
        mg8<256, 1><<<dim3(8, 64), blk512, 0, stream>>>(
            xb, 512, W1T_l, 512, b1 + l * 2048, hidden, 2048, 512);
        mg8<128, 0><<<dim3(4, 64), blk512, 0, stream>>>(
            hidden, 2048, W2T_l, 2048, b2 + l * 512, ffout, 512, 2048);
        addln_k<<<dim3(8192), blk, 0, stream>>>(
            xb, ffout, 0xffffffffu, ln2_g + l * 512, ln2_b + l * 512);
    }

    // ---- out = x @ fc_W + fc_b ----
    fc_k<<<dim3(4096), blk, 0, stream>>>(xb, fcW, fcb, out);
}